// Round 11
// baseline (726.804 us; speedup 1.0000x reference)
//
#include <hip/hip_runtime.h>
#include <hip/hip_bf16.h>
#include <math.h>

#define BN_ 32
#define CIN 512
#define KN 1024
#define CMID 128
#define COUT 64
#define NCLS 5
#define NUM_TOP 205
#define NUM_KEPT 409
#define NUM_DROP 410
#define ADJ_KK 204
#define EPSF 1e-8f
#define INV_DS (1.0f / 0.599609375f)

typedef __bf16 bf16x8 __attribute__((ext_vector_type(8)));
typedef float f32x4 __attribute__((ext_vector_type(4)));

__device__ inline ushort f2bf(float x) {
  union { __hip_bfloat16 b; ushort u; } c;
  c.b = __float2bfloat16(x);
  return c.u;
}

// async global->LDS, 16B per lane (dest = wave-uniform base + lane*16)
__device__ inline void gll16(const ushort* g, ushort* l) {
  __builtin_amdgcn_global_load_lds(
      (const __attribute__((address_space(1))) unsigned int*)g,
      (__attribute__((address_space(3))) unsigned int*)l, 16, 0, 0);
}

// ---------------- masks stage 1: top mask via rank counting --------------
__global__ __launch_bounds__(256) void masks1_kernel(const float* __restrict__ imp,
                                                     float* __restrict__ topM) {
  int b = blockIdx.y;
  int i = blockIdx.x * 256 + threadIdx.x;
  __shared__ float im[KN];
  for (int j = threadIdx.x; j < KN; j += 256) im[j] = imp[(size_t)b * KN + j];
  __syncthreads();
  float vi = im[i];
  int r0 = 0, r1 = 0, r2 = 0, r3 = 0;
  for (int j = 0; j < KN; j += 4) {
    float a0 = im[j], a1 = im[j + 1], a2 = im[j + 2], a3 = im[j + 3];
    r0 += (a0 > vi || (a0 == vi && j < i)) ? 1 : 0;
    r1 += (a1 > vi || (a1 == vi && j + 1 < i)) ? 1 : 0;
    r2 += (a2 > vi || (a2 == vi && j + 2 < i)) ? 1 : 0;
    r3 += (a3 > vi || (a3 == vi && j + 3 < i)) ? 1 : 0;
  }
  int rank = r0 + r1 + r2 + r3;
  topM[(size_t)b * KN + i] = (rank < NUM_TOP) ? 1.0f : 0.0f;
}

// ---------------- masks stage 2: kept/drop ranks, fused ------------------
__global__ __launch_bounds__(256) void masks2_kernel(const float* __restrict__ rnd,
                                                     const float* __restrict__ topM,
                                                     float* __restrict__ mTK,
                                                     float* __restrict__ mTD) {
  int b = blockIdx.y;
  int i = blockIdx.x * 256 + threadIdx.x;
  __shared__ float r1s[KN];
  __shared__ float r2s[KN];
  for (int j = threadIdx.x; j < KN; j += 256) {
    float tv = topM[(size_t)b * KN + j];
    float rv = rnd[(size_t)b * KN + j];
    r1s[j] = (tv > 0.5f) ? -10.0f : rv;
    r2s[j] = (tv > 0.5f) ? 10.0f : rv;
  }
  __syncthreads();
  float v1 = r1s[i];
  float v2 = r2s[i];
  int c1a = 0, c1b = 0, c2a = 0, c2b = 0;
  for (int j = 0; j < KN; j += 2) {
    float a0 = r1s[j], a1 = r1s[j + 1];
    float b0 = r2s[j], b1 = r2s[j + 1];
    c1a += (a0 > v1 || (a0 == v1 && j < i)) ? 1 : 0;
    c1b += (a1 > v1 || (a1 == v1 && j + 1 < i)) ? 1 : 0;
    c2a += (b0 < v2 || (b0 == v2 && j < i)) ? 1 : 0;
    c2b += (b1 < v2 || (b1 == v2 && j + 1 < i)) ? 1 : 0;
  }
  int kept = (c1a + c1b) < NUM_KEPT;
  int drop = (c2a + c2b) < NUM_DROP;
  int top = topM[(size_t)b * KN + i] > 0.5f;
  mTK[(size_t)b * KN + i] = (top || kept) ? 1.0f : 0.0f;
  mTD[(size_t)b * KN + i] = (top || drop) ? 1.0f : 0.0f;
}

// ---------------- adjP row-sum reciprocals -------------------------------
__global__ void psum_kernel(const float* __restrict__ imp, float* __restrict__ invSumP) {
  int b = blockIdx.y;
  int i = blockIdx.x * 256 + threadIdx.x;
  __shared__ float im[KN];
  for (int j = threadIdx.x; j < KN; j += 256) im[j] = imp[(size_t)b * KN + j];
  __syncthreads();
  float vi = im[i];
  float s = 0.0f;
  for (int j = 0; j < KN; ++j) {
    float d = vi - im[j];
    s += __expf(-d * d * 0.125f);
  }
  invSumP[(size_t)b * KN + i] = 1.0f / (s + 1.0f + EPSF);
}

// ---------------- per-column L2 norm reciprocals -------------------------
template <int C>
__global__ void colnorm_kernel(const float* __restrict__ f, float* __restrict__ inv) {
  int idx = blockIdx.x * 256 + threadIdx.x;
  int b = idx >> 10;
  int k = idx & (KN - 1);
  const float* fb = f + (size_t)b * C * KN + k;
  float ss = 0.0f;
  for (int c = 0; c < C; ++c) {
    float v = fb[(size_t)c * KN];
    ss += v * v;
  }
  inv[idx] = 1.0f / (sqrtf(ss) + EPSF);
}

// ------- transpose + normalize + bf16: oT[b][k][c] = f[b][c][k]*inv[b][k] --
template <int C>
__global__ void xpose_kernel(const float* __restrict__ f, const float* __restrict__ inv,
                             __hip_bfloat16* __restrict__ oT) {
  int b = blockIdx.z;
  int k0 = blockIdx.x * 64;
  int c0 = blockIdx.y * 64;
  __shared__ float t[64][65];
  const float* fb = f + (size_t)b * C * KN;
  int tx = threadIdx.x & 63;
  int ty = threadIdx.x >> 6;
  for (int r = 0; r < 64; r += 4) t[r + ty][tx] = fb[(size_t)(c0 + r + ty) * KN + k0 + tx];
  __syncthreads();
  __hip_bfloat16* ob = oT + (size_t)b * KN * C;
  for (int r = 0; r < 64; r += 4) {
    int k = r + ty;
    float s = inv[(size_t)b * KN + k0 + k];
    ob[(size_t)(k0 + k) * C + c0 + tx] = __float2bfloat16(t[tx][k] * s);
  }
}

// ---------------- MFMA sim: sim = XnT * XnT^T (Gram, symmetric) ----------
template <int C>
__global__ __launch_bounds__(256) void simf_kernel(const ushort* __restrict__ xT,
                                                   float* __restrict__ sim, int bstart, int nb) {
  int f = blockIdx.x;
  int brel, tile;
  if ((nb & 7) == 0) {
    int xcd = f & 7;
    int wdx = f >> 3;
    brel = xcd * (nb >> 3) + (wdx >> 6);
    tile = wdx & 63;
  } else {
    brel = f >> 6;
    tile = f & 63;
  }
  int b = bstart + brel;
  int t = threadIdx.x;
  int lane = t & 63;
  int wid = t >> 6;
  int iB = (tile >> 3) * 128;
  int jB = (tile & 7) * 128;
  const ushort* X = xT + (size_t)b * KN * C;

  __shared__ ushort As[2][128 * 32];
  __shared__ ushort Bs[2][128 * 32];
  __shared__ float ep[4][16][65];

  int srow = t >> 2;
  int scol = (t & 3) * 8;
  int ldst = t * 8;

  auto stage = [&](int buf, int c0) {
    gll16(X + (size_t)(iB + srow) * C + c0 + scol, &As[buf][ldst]);
    gll16(X + (size_t)(iB + 64 + srow) * C + c0 + scol, &As[buf][2048 + ldst]);
    gll16(X + (size_t)(jB + srow) * C + c0 + scol, &Bs[buf][ldst]);
    gll16(X + (size_t)(jB + 64 + srow) * C + c0 + scol, &Bs[buf][2048 + ldst]);
  };

  int i0loc = (wid >> 1) * 64;
  int j0loc = (wid & 1) * 64;
  int r = lane & 15;
  int s = (lane >> 4) * 8;

  f32x4 acc[4][4] = {};
  stage(0, 0);
  __syncthreads();
  constexpr int NT = C / 32;
  int cur = 0;
#pragma unroll 2
  for (int ks = 0; ks < NT; ++ks) {
    if (ks + 1 < NT) stage(cur ^ 1, (ks + 1) * 32);
    bf16x8 a[4], bb[4];
#pragma unroll
    for (int m = 0; m < 4; ++m)
      a[m] = *reinterpret_cast<const bf16x8*>(&As[cur][(i0loc + m * 16 + r) * 32 + s]);
#pragma unroll
    for (int n = 0; n < 4; ++n)
      bb[n] = *reinterpret_cast<const bf16x8*>(&Bs[cur][(j0loc + n * 16 + r) * 32 + s]);
#pragma unroll
    for (int m = 0; m < 4; ++m)
#pragma unroll
      for (int n = 0; n < 4; ++n)
        acc[m][n] = __builtin_amdgcn_mfma_f32_16x16x32_bf16(a[m], bb[n], acc[m][n], 0, 0, 0);
    __syncthreads();
    cur ^= 1;
  }

  float(*buf)[65] = ep[wid];
  int orow = (lane >> 4) * 4;
  int ocol = lane & 15;
  int i0 = iB + i0loc;
  int j0 = jB + j0loc;
  float* simb = sim + (size_t)brel * KN * KN;
#pragma unroll
  for (int m = 0; m < 4; ++m) {
#pragma unroll
    for (int n = 0; n < 4; ++n)
#pragma unroll
      for (int rr = 0; rr < 4; ++rr) buf[orow + rr][n * 16 + ocol] = acc[m][n][rr];
#pragma unroll
    for (int rr = 0; rr < 4; ++rr) {
      int row = rr * 4 + (lane >> 4);
      float4 v4 = *(const float4*)&buf[row][(lane & 15) * 4];
      *(float4*)(simb + (size_t)(i0 + m * 16 + row) * KN + j0 + (lane & 15) * 4) = v4;
    }
  }
}

// ------- fused per-wave threshold select + finalize ----------------------
__global__ __launch_bounds__(256) void thrfin_kernel(float* __restrict__ A,
                                                     const float* __restrict__ imp,
                                                     const float* __restrict__ invSumP,
                                                     int bstart) {
  int brel = blockIdx.y;
  int b = bstart + brel;
  int wid = threadIdx.x >> 6;
  int lane = threadIdx.x & 63;
  int i = blockIdx.x * 4 + wid;
  float* row = A + ((size_t)brel * KN + i) * KN;
  __shared__ float im[KN];
  ((float4*)im)[threadIdx.x] = ((const float4*)(imp + (size_t)b * KN))[threadIdx.x];
  __syncthreads();

  float4 v[4];
  unsigned key[16];
#pragma unroll
  for (int q = 0; q < 4; ++q) v[q] = ((const float4*)row)[lane + 64 * q];
#pragma unroll
  for (int q = 0; q < 4; ++q) {
    const float* pv = (const float*)&v[q];
#pragma unroll
    for (int e = 0; e < 4; ++e) {
      unsigned u = __float_as_uint(pv[e]);
      key[q * 4 + e] = (u & 0x80000000u) ? ~u : (u | 0x80000000u);
    }
  }
  unsigned tk = 0u;
#pragma unroll 1
  for (int bit = 31; bit >= 0; --bit) {
    unsigned cand = tk | (1u << bit);
    int c = 0;
#pragma unroll
    for (int e = 0; e < 16; ++e) c += (key[e] >= cand) ? 1 : 0;
#pragma unroll
    for (int off = 32; off > 0; off >>= 1) c += __shfl_xor(c, off);
    if (c >= ADJ_KK) tk = cand;
  }
  float m[16];
  float s = 0.0f;
#pragma unroll
  for (int q = 0; q < 4; ++q) {
    const float* pv = (const float*)&v[q];
#pragma unroll
    for (int e = 0; e < 4; ++e) {
      float mv = (key[q * 4 + e] >= tk) ? pv[e] : 0.0f;
      m[q * 4 + e] = mv;
      s += mv;
    }
  }
#pragma unroll
  for (int off = 32; off > 0; off >>= 1) s += __shfl_xor(s, off);
  float invF = 1.0f / (s + 1.0f + EPSF);
  float vi = im[i];
  float invP = invSumP[(size_t)b * KN + i];
  ushort* rowb = (ushort*)row;
#pragma unroll
  for (int q = 0; q < 4; ++q) {
    float4 iv = ((const float4*)im)[lane + 64 * q];
    const float* ip = (const float*)&iv;
    ushort4 r;
    ushort* rp = (ushort*)&r;
    int colb = 4 * lane + 256 * q;
#pragma unroll
    for (int e = 0; e < 4; ++e) {
      float diag = (colb + e == i) ? 1.0f : 0.0f;
      float d = vi - ip[e];
      rp[e] = f2bf((m[q * 4 + e] + diag) * invF + (__expf(-d * d * 0.125f) + diag) * invP);
    }
    ((ushort4*)rowb)[lane + 64 * q] = r;
  }
}

// ------- bf16 transpose: At[b][j][k] = A[b][k][j] (A row stride 2048) ----
__global__ void at_kernel(const float* __restrict__ Asim, ushort* __restrict__ At) {
  int brel = blockIdx.z;
  int k0 = blockIdx.x * 64;
  int j0 = blockIdx.y * 64;
  __shared__ ushort t[64][65];
  const ushort* Ab = (const ushort*)(Asim + (size_t)brel * KN * KN);
  int tx = threadIdx.x & 63;
  int ty = threadIdx.x >> 6;
  for (int r = 0; r < 64; r += 4) t[r + ty][tx] = Ab[(size_t)(k0 + r + ty) * 2048 + j0 + tx];
  __syncthreads();
  ushort* ob = At + (size_t)brel * KN * KN;
  for (int r = 0; r < 64; r += 4) ob[(size_t)(j0 + r + ty) * KN + k0 + tx] = t[tx][r + ty];
}

// ---------------- per-node linear: h[b,o,k] = sum_c f[b,c,k] W[c,o] (bf16 out)
// o-tile 16 (8 FLOP/byte on f), k-split 2 for occupancy; W read via
// wave-uniform address -> scalar s_load broadcast, no LDS, no barriers.
// b-major flat grid (stride 32 = 0 mod 8) keeps batch b's blocks on one XCD.
template <int C, int M, bool MASK>
__global__ __launch_bounds__(256) void linear_kernel(const float* __restrict__ f,
                                                     const float* __restrict__ W,
                                                     ushort* __restrict__ outp,
                                                     const float* __restrict__ mTK) {
  int fl = blockIdx.x;
  int b = fl & 31;
  int t2 = fl >> 5;
  int o0 = (t2 >> 1) * 16;
  int k0 = (t2 & 1) * (KN / 2) + threadIdx.x * 2;
  const float* fb = f + (size_t)b * C * KN;
  float accx[16] = {};
  float accy[16] = {};
  for (int c = 0; c < C; ++c) {
    float2 xv = *(const float2*)(fb + (size_t)c * KN + k0);
    const float* wr = W + (size_t)c * M + o0;
#pragma unroll
    for (int o = 0; o < 16; ++o) {
      float w = wr[o];
      accx[o] += xv.x * w;
      accy[o] += xv.y * w;
    }
  }
  float ms0 = 1.0f, ms1 = 1.0f;
  if (MASK) {
    ms0 = mTK[(size_t)b * KN + k0] * INV_DS;
    ms1 = mTK[(size_t)b * KN + k0 + 1] * INV_DS;
  }
#pragma unroll
  for (int o = 0; o < 16; ++o) {
    ushort2 r;
    r.x = f2bf(accx[o] * ms0);
    r.y = f2bf(accy[o] * ms1);
    *(ushort2*)(outp + ((size_t)b * M + o0 + o) * KN + k0) = r;
  }
}

// ---------------- MFMA s = relu(h @ A) via At, LDS-staged ----------------
template <int M>
__global__ __launch_bounds__(256) void sgemmf_kernel(const ushort* __restrict__ hB,
                                                     const ushort* __restrict__ At,
                                                     float* __restrict__ outp, int bstart) {
  int brel = blockIdx.z;
  int b = bstart + brel;
  int t = threadIdx.x;
  int lane = t & 63;
  int wid = t >> 6;
  int iB = blockIdx.y * 64;
  int jB = blockIdx.x * 128;
  const ushort* hb = hB + (size_t)b * M * KN;
  const ushort* Ab = At + (size_t)brel * KN * KN;

  __shared__ ushort Hs[2][64 * 32];
  __shared__ ushort Bs[2][128 * 32];
  __shared__ float ep[4][16][65];

  int srow = t >> 2;
  int scol = (t & 3) * 8;
  int ldst = t * 8;

  auto stage = [&](int buf, int k0) {
    gll16(hb + (size_t)(iB + srow) * KN + k0 + scol, &Hs[buf][ldst]);
    gll16(Ab + (size_t)(jB + srow) * KN + k0 + scol, &Bs[buf][ldst]);
    gll16(Ab + (size_t)(jB + 64 + srow) * KN + k0 + scol, &Bs[buf][2048 + ldst]);
  };

  int i0loc = (wid >> 1) * 32;
  int j0loc = (wid & 1) * 64;
  int r = lane & 15;
  int s = (lane >> 4) * 8;

  f32x4 acc[2][4] = {};
  stage(0, 0);
  __syncthreads();
  int cur = 0;
#pragma unroll 2
  for (int ks = 0; ks < KN / 32; ++ks) {
    if (ks + 1 < KN / 32) stage(cur ^ 1, (ks + 1) * 32);
    bf16x8 a[2], bb[4];
#pragma unroll
    for (int m = 0; m < 2; ++m)
      a[m] = *reinterpret_cast<const bf16x8*>(&Hs[cur][(i0loc + m * 16 + r) * 32 + s]);
#pragma unroll
    for (int n = 0; n < 4; ++n)
      bb[n] = *reinterpret_cast<const bf16x8*>(&Bs[cur][(j0loc + n * 16 + r) * 32 + s]);
#pragma unroll
    for (int m = 0; m < 2; ++m)
#pragma unroll
      for (int n = 0; n < 4; ++n)
        acc[m][n] = __builtin_amdgcn_mfma_f32_16x16x32_bf16(a[m], bb[n], acc[m][n], 0, 0, 0);
    __syncthreads();
    cur ^= 1;
  }

  float(*buf)[65] = ep[wid];
  int orow = (lane >> 4) * 4;
  int ocol = lane & 15;
  int i0 = iB + i0loc;
  int j0 = jB + j0loc;
  float* ob = outp + (size_t)b * M * KN;
#pragma unroll
  for (int m = 0; m < 2; ++m) {
#pragma unroll
    for (int n = 0; n < 4; ++n)
#pragma unroll
      for (int rr = 0; rr < 4; ++rr) buf[orow + rr][n * 16 + ocol] = fmaxf(acc[m][n][rr], 0.0f);
#pragma unroll
    for (int rr = 0; rr < 4; ++rr) {
      int row = rr * 4 + (lane >> 4);
      float4 v4 = *(const float4*)&buf[row][(lane & 15) * 4];
      *(float4*)(ob + (size_t)(i0 + m * 16 + row) * KN + j0 + (lane & 15) * 4) = v4;
    }
  }
}

// ---------------- reductions ---------------------------------------------
__global__ void bag12_kernel(const float* __restrict__ emb1, const float* __restrict__ mTK,
                             const float* __restrict__ mTD, const float* __restrict__ imp,
                             float* __restrict__ bagk, float* __restrict__ bagd) {
  int c = blockIdx.x, b = blockIdx.y;
  int t = threadIdx.x;
  const float* e = emb1 + ((size_t)b * CMID + c) * KN;
  const float* ir = imp + (size_t)b * KN;
  const float* m1 = mTK + (size_t)b * KN;
  const float* m2 = mTD + (size_t)b * KN;
  float s1 = 0.0f, sd = 0.0f;
  for (int k = t; k < KN; k += 256) {
    float ev = e[k] * ir[k];
    s1 += ev * m1[k];
    sd += ev * m2[k];
  }
  __shared__ float r1[256], r2[256];
  r1[t] = s1;
  r2[t] = sd;
  __syncthreads();
  for (int st = 128; st > 0; st >>= 1) {
    if (t < st) {
      r1[t] += r1[t + st];
      r2[t] += r2[t + st];
    }
    __syncthreads();
  }
  if (t == 0) {
    bagk[(size_t)b * CMID + c] = r1[0] * INV_DS;
    bagd[(size_t)b * CMID + c] = r2[0] * INV_DS;
  }
}

__global__ void bag2_kernel(const float* __restrict__ s2, const float* __restrict__ mTK,
                            const float* __restrict__ imp, float* __restrict__ bag) {
  int o = blockIdx.x, b = blockIdx.y;
  int t = threadIdx.x;
  const float* sr = s2 + ((size_t)b * COUT + o) * KN;
  const float* ir = imp + (size_t)b * KN;
  const float* mr = mTK + (size_t)b * KN;
  float s = 0.0f;
  for (int k = t; k < KN; k += 256) s += sr[k] * mr[k] * ir[k];
  __shared__ float red[256];
  red[t] = s;
  __syncthreads();
  for (int st = 128; st > 0; st >>= 1) {
    if (t < st) red[t] += red[t + st];
    __syncthreads();
  }
  if (t == 0) bag[(size_t)b * COUT + o] = red[0];
}

__global__ void pooled_kernel(const float* __restrict__ x, const float* __restrict__ imp,
                              float* __restrict__ pooled) {
  int c = blockIdx.x, b = blockIdx.y;
  int t = threadIdx.x;
  const float* xr = x + ((size_t)b * CIN + c) * KN;
  const float* ir = imp + (size_t)b * KN;
  float s = 0.0f;
  for (int k = t; k < KN; k += 256) s += xr[k] * ir[k];
  __shared__ float red[256];
  red[t] = s;
  __syncthreads();
  for (int st = 128; st > 0; st >>= 1) {
    if (t < st) red[t] += red[t + st];
    __syncthreads();
  }
  if (t == 0) pooled[(size_t)b * CIN + c] = red[0];
}

__global__ void final_kernel(const float* __restrict__ pooled, const float* __restrict__ bag,
                             const float* __restrict__ id_w, const float* __restrict__ id_b,
                             const float* __restrict__ fc_w, float* __restrict__ out) {
  int b = blockIdx.x;
  int o = threadIdx.x;
  __shared__ float v[COUT];
  float s = id_b[o];
  const float* pr = pooled + (size_t)b * CIN;
  for (int c = 0; c < CIN; ++c) s += pr[c] * id_w[(size_t)c * COUT + o];
  v[o] = bag[(size_t)b * COUT + o] + fmaxf(s, 0.0f);
  __syncthreads();
  if (o < NCLS) {
    float acc = 0.0f;
    for (int oo = 0; oo < COUT; ++oo) acc += v[oo] * fc_w[(size_t)oo * NCLS + o];
    out[(size_t)b * NCLS + o] = acc;
  }
}

// ---------------- launch --------------------------------------------------
extern "C" void kernel_launch(void* const* d_in, const int* in_sizes, int n_in,
                              void* d_out, int out_size, void* d_ws, size_t ws_size,
                              hipStream_t stream) {
  const float* x = (const float*)d_in[0];
  const float* imp = (const float*)d_in[1];
  const float* rnd = (const float*)d_in[2];
  const float* W1 = (const float*)d_in[3];
  const float* W2 = (const float*)d_in[4];
  const float* fc_w = (const float*)d_in[5];
  const float* id_w = (const float*)d_in[6];
  const float* id_b = (const float*)d_in[7];
  float* out = (float*)d_out;
  float* emb1 = out + BN_ * NCLS;
  float* bagk = emb1 + (size_t)BN_ * CMID * KN;
  float* bagd = bagk + (size_t)BN_ * CMID;

  float* w = (float*)d_ws;
  size_t off = 0;
  auto take = [&](size_t n) {
    float* p = w + off;
    off += n;
    return p;
  };
  float* invSumP = take((size_t)BN_ * KN);
  float* invNX = take((size_t)BN_ * KN);
  float* invNE = take((size_t)BN_ * KN);
  float* topM = take((size_t)BN_ * KN);
  float* mTK = take((size_t)BN_ * KN);
  float* mTD = take((size_t)BN_ * KN);
  ushort* h = (ushort*)take((size_t)BN_ * CMID * KN / 2);
  ushort* h2 = (ushort*)take((size_t)BN_ * COUT * KN / 2);
  float* s2 = take((size_t)BN_ * COUT * KN);
  float* bag = take((size_t)BN_ * COUT);
  float* pooled = take((size_t)BN_ * CIN);
  ushort* xnT = (ushort*)take((size_t)BN_ * CIN * KN / 2);
  ushort* enT = (ushort*)take((size_t)BN_ * CMID * KN / 2);
  long long avail = (long long)(ws_size / 4) - (long long)off;
  int nb = 1;
  const int cands[6] = {32, 16, 8, 4, 2, 1};
  for (int ci = 0; ci < 6; ++ci) {
    if ((long long)cands[ci] * KN * KN * 3 / 2 <= avail) {
      nb = cands[ci];
      break;
    }
  }
  float* simA = take((size_t)nb * KN * KN);
  ushort* At = (ushort*)take((size_t)nb * KN * KN / 2);

  masks1_kernel<<<dim3(KN / 256, BN_), 256, 0, stream>>>(imp, topM);
  masks2_kernel<<<dim3(KN / 256, BN_), 256, 0, stream>>>(rnd, topM, mTK, mTD);
  psum_kernel<<<dim3(KN / 256, BN_), 256, 0, stream>>>(imp, invSumP);
  colnorm_kernel<CIN><<<(BN_ * KN) / 256, 256, 0, stream>>>(x, invNX);
  xpose_kernel<CIN><<<dim3(KN / 64, CIN / 64, BN_), 256, 0, stream>>>(x, invNX,
                                                                      (__hip_bfloat16*)xnT);
  linear_kernel<CIN, CMID, false><<<(CMID / 16) * 2 * BN_, 256, 0, stream>>>(x, W1, h, nullptr);

  for (int bs = 0; bs < BN_; bs += nb) {
    simf_kernel<CIN><<<nb * 64, 256, 0, stream>>>(xnT, simA, bs, nb);
    thrfin_kernel<<<dim3(KN / 4, nb), 256, 0, stream>>>(simA, imp, invSumP, bs);
    at_kernel<<<dim3(KN / 64, KN / 64, nb), 256, 0, stream>>>(simA, At);
    sgemmf_kernel<CMID><<<dim3(KN / 128, CMID / 64, nb), 256, 0, stream>>>(h, At, emb1, bs);
  }

  colnorm_kernel<CMID><<<(BN_ * KN) / 256, 256, 0, stream>>>(emb1, invNE);
  xpose_kernel<CMID><<<dim3(KN / 64, CMID / 64, BN_), 256, 0, stream>>>(emb1, invNE,
                                                                        (__hip_bfloat16*)enT);
  linear_kernel<CMID, COUT, true><<<(COUT / 16) * 2 * BN_, 256, 0, stream>>>(emb1, W2, h2, mTK);

  for (int bs = 0; bs < BN_; bs += nb) {
    simf_kernel<CMID><<<nb * 64, 256, 0, stream>>>(enT, simA, bs, nb);
    thrfin_kernel<<<dim3(KN / 4, nb), 256, 0, stream>>>(simA, imp, invSumP, bs);
    at_kernel<<<dim3(KN / 64, KN / 64, nb), 256, 0, stream>>>(simA, At);
    sgemmf_kernel<COUT><<<dim3(KN / 128, COUT / 64, nb), 256, 0, stream>>>(h2, At, s2, bs);
  }

  bag12_kernel<<<dim3(CMID, BN_), 256, 0, stream>>>(emb1, mTK, mTD, imp, bagk, bagd);
  bag2_kernel<<<dim3(COUT, BN_), 256, 0, stream>>>(s2, mTK, imp, bag);
  pooled_kernel<<<dim3(CIN, BN_), 256, 0, stream>>>(x, imp, pooled);
  final_kernel<<<BN_, 64, 0, stream>>>(pooled, bag, id_w, id_b, fc_w, out);
}

// Round 12
// 666.748 us; speedup vs baseline: 1.0901x; 1.0901x over previous
//
#include <hip/hip_runtime.h>
#include <hip/hip_bf16.h>
#include <math.h>

#define BN_ 32
#define CIN 512
#define KN 1024
#define CMID 128
#define COUT 64
#define NCLS 5
#define NUM_TOP 205
#define NUM_KEPT 409
#define NUM_DROP 410
#define ADJ_KK 204
#define EPSF 1e-8f
#define INV_DS (1.0f / 0.599609375f)

typedef __bf16 bf16x8 __attribute__((ext_vector_type(8)));
typedef float f32x4 __attribute__((ext_vector_type(4)));

__device__ inline ushort f2bf(float x) {
  union { __hip_bfloat16 b; ushort u; } c;
  c.b = __float2bfloat16(x);
  return c.u;
}

// async global->LDS, 16B per lane (dest = wave-uniform base + lane*16)
__device__ inline void gll16(const ushort* g, ushort* l) {
  __builtin_amdgcn_global_load_lds(
      (const __attribute__((address_space(1))) unsigned int*)g,
      (__attribute__((address_space(3))) unsigned int*)l, 16, 0, 0);
}

// ---------------- masks stage 1: top mask via rank counting --------------
__global__ __launch_bounds__(256) void masks1_kernel(const float* __restrict__ imp,
                                                     float* __restrict__ topM) {
  int b = blockIdx.y;
  int i = blockIdx.x * 256 + threadIdx.x;
  __shared__ float im[KN];
  for (int j = threadIdx.x; j < KN; j += 256) im[j] = imp[(size_t)b * KN + j];
  __syncthreads();
  float vi = im[i];
  int r0 = 0, r1 = 0, r2 = 0, r3 = 0;
  for (int j = 0; j < KN; j += 4) {
    float a0 = im[j], a1 = im[j + 1], a2 = im[j + 2], a3 = im[j + 3];
    r0 += (a0 > vi || (a0 == vi && j < i)) ? 1 : 0;
    r1 += (a1 > vi || (a1 == vi && j + 1 < i)) ? 1 : 0;
    r2 += (a2 > vi || (a2 == vi && j + 2 < i)) ? 1 : 0;
    r3 += (a3 > vi || (a3 == vi && j + 3 < i)) ? 1 : 0;
  }
  int rank = r0 + r1 + r2 + r3;
  topM[(size_t)b * KN + i] = (rank < NUM_TOP) ? 1.0f : 0.0f;
}

// ---------------- masks stage 2: kept/drop ranks, fused ------------------
__global__ __launch_bounds__(256) void masks2_kernel(const float* __restrict__ rnd,
                                                     const float* __restrict__ topM,
                                                     float* __restrict__ mTK,
                                                     float* __restrict__ mTD) {
  int b = blockIdx.y;
  int i = blockIdx.x * 256 + threadIdx.x;
  __shared__ float r1s[KN];
  __shared__ float r2s[KN];
  for (int j = threadIdx.x; j < KN; j += 256) {
    float tv = topM[(size_t)b * KN + j];
    float rv = rnd[(size_t)b * KN + j];
    r1s[j] = (tv > 0.5f) ? -10.0f : rv;
    r2s[j] = (tv > 0.5f) ? 10.0f : rv;
  }
  __syncthreads();
  float v1 = r1s[i];
  float v2 = r2s[i];
  int c1a = 0, c1b = 0, c2a = 0, c2b = 0;
  for (int j = 0; j < KN; j += 2) {
    float a0 = r1s[j], a1 = r1s[j + 1];
    float b0 = r2s[j], b1 = r2s[j + 1];
    c1a += (a0 > v1 || (a0 == v1 && j < i)) ? 1 : 0;
    c1b += (a1 > v1 || (a1 == v1 && j + 1 < i)) ? 1 : 0;
    c2a += (b0 < v2 || (b0 == v2 && j < i)) ? 1 : 0;
    c2b += (b1 < v2 || (b1 == v2 && j + 1 < i)) ? 1 : 0;
  }
  int kept = (c1a + c1b) < NUM_KEPT;
  int drop = (c2a + c2b) < NUM_DROP;
  int top = topM[(size_t)b * KN + i] > 0.5f;
  mTK[(size_t)b * KN + i] = (top || kept) ? 1.0f : 0.0f;
  mTD[(size_t)b * KN + i] = (top || drop) ? 1.0f : 0.0f;
}

// ---------------- adjP row-sum reciprocals -------------------------------
__global__ void psum_kernel(const float* __restrict__ imp, float* __restrict__ invSumP) {
  int b = blockIdx.y;
  int i = blockIdx.x * 256 + threadIdx.x;
  __shared__ float im[KN];
  for (int j = threadIdx.x; j < KN; j += 256) im[j] = imp[(size_t)b * KN + j];
  __syncthreads();
  float vi = im[i];
  float s = 0.0f;
  for (int j = 0; j < KN; ++j) {
    float d = vi - im[j];
    s += __expf(-d * d * 0.125f);
  }
  invSumP[(size_t)b * KN + i] = 1.0f / (s + 1.0f + EPSF);
}

// ---------------- per-column L2 norm reciprocals -------------------------
template <int C>
__global__ void colnorm_kernel(const float* __restrict__ f, float* __restrict__ inv) {
  int idx = blockIdx.x * 256 + threadIdx.x;
  int b = idx >> 10;
  int k = idx & (KN - 1);
  const float* fb = f + (size_t)b * C * KN + k;
  float ss = 0.0f;
  for (int c = 0; c < C; ++c) {
    float v = fb[(size_t)c * KN];
    ss += v * v;
  }
  inv[idx] = 1.0f / (sqrtf(ss) + EPSF);
}

// ------- transpose + normalize + bf16: oT[b][k][c] = f[b][c][k]*inv[b][k] --
template <int C>
__global__ void xpose_kernel(const float* __restrict__ f, const float* __restrict__ inv,
                             __hip_bfloat16* __restrict__ oT) {
  int b = blockIdx.z;
  int k0 = blockIdx.x * 64;
  int c0 = blockIdx.y * 64;
  __shared__ float t[64][65];
  const float* fb = f + (size_t)b * C * KN;
  int tx = threadIdx.x & 63;
  int ty = threadIdx.x >> 6;
  for (int r = 0; r < 64; r += 4) t[r + ty][tx] = fb[(size_t)(c0 + r + ty) * KN + k0 + tx];
  __syncthreads();
  __hip_bfloat16* ob = oT + (size_t)b * KN * C;
  for (int r = 0; r < 64; r += 4) {
    int k = r + ty;
    float s = inv[(size_t)b * KN + k0 + k];
    ob[(size_t)(k0 + k) * C + c0 + tx] = __float2bfloat16(t[tx][k] * s);
  }
}

// ---------------- MFMA sim: sim = XnT * XnT^T (Gram, symmetric) ----------
template <int C>
__global__ __launch_bounds__(256) void simf_kernel(const ushort* __restrict__ xT,
                                                   float* __restrict__ sim, int bstart, int nb) {
  int f = blockIdx.x;
  int brel, tile;
  if ((nb & 7) == 0) {
    int xcd = f & 7;
    int wdx = f >> 3;
    brel = xcd * (nb >> 3) + (wdx >> 6);
    tile = wdx & 63;
  } else {
    brel = f >> 6;
    tile = f & 63;
  }
  int b = bstart + brel;
  int t = threadIdx.x;
  int lane = t & 63;
  int wid = t >> 6;
  int iB = (tile >> 3) * 128;
  int jB = (tile & 7) * 128;
  const ushort* X = xT + (size_t)b * KN * C;

  __shared__ ushort As[2][128 * 32];
  __shared__ ushort Bs[2][128 * 32];
  __shared__ float ep[4][16][65];

  int srow = t >> 2;
  int scol = (t & 3) * 8;
  int ldst = t * 8;

  auto stage = [&](int buf, int c0) {
    gll16(X + (size_t)(iB + srow) * C + c0 + scol, &As[buf][ldst]);
    gll16(X + (size_t)(iB + 64 + srow) * C + c0 + scol, &As[buf][2048 + ldst]);
    gll16(X + (size_t)(jB + srow) * C + c0 + scol, &Bs[buf][ldst]);
    gll16(X + (size_t)(jB + 64 + srow) * C + c0 + scol, &Bs[buf][2048 + ldst]);
  };

  int i0loc = (wid >> 1) * 64;
  int j0loc = (wid & 1) * 64;
  int r = lane & 15;
  int s = (lane >> 4) * 8;

  f32x4 acc[4][4] = {};
  stage(0, 0);
  __syncthreads();
  constexpr int NT = C / 32;
  int cur = 0;
#pragma unroll 2
  for (int ks = 0; ks < NT; ++ks) {
    if (ks + 1 < NT) stage(cur ^ 1, (ks + 1) * 32);
    bf16x8 a[4], bb[4];
#pragma unroll
    for (int m = 0; m < 4; ++m)
      a[m] = *reinterpret_cast<const bf16x8*>(&As[cur][(i0loc + m * 16 + r) * 32 + s]);
#pragma unroll
    for (int n = 0; n < 4; ++n)
      bb[n] = *reinterpret_cast<const bf16x8*>(&Bs[cur][(j0loc + n * 16 + r) * 32 + s]);
#pragma unroll
    for (int m = 0; m < 4; ++m)
#pragma unroll
      for (int n = 0; n < 4; ++n)
        acc[m][n] = __builtin_amdgcn_mfma_f32_16x16x32_bf16(a[m], bb[n], acc[m][n], 0, 0, 0);
    __syncthreads();
    cur ^= 1;
  }

  float(*buf)[65] = ep[wid];
  int orow = (lane >> 4) * 4;
  int ocol = lane & 15;
  int i0 = iB + i0loc;
  int j0 = jB + j0loc;
  float* simb = sim + (size_t)brel * KN * KN;
#pragma unroll
  for (int m = 0; m < 4; ++m) {
#pragma unroll
    for (int n = 0; n < 4; ++n)
#pragma unroll
      for (int rr = 0; rr < 4; ++rr) buf[orow + rr][n * 16 + ocol] = acc[m][n][rr];
#pragma unroll
    for (int rr = 0; rr < 4; ++rr) {
      int row = rr * 4 + (lane >> 4);
      float4 v4 = *(const float4*)&buf[row][(lane & 15) * 4];
      *(float4*)(simb + (size_t)(i0 + m * 16 + row) * KN + j0 + (lane & 15) * 4) = v4;
    }
  }
}

// ------- fused per-wave threshold select + finalize ----------------------
__global__ __launch_bounds__(256) void thrfin_kernel(float* __restrict__ A,
                                                     const float* __restrict__ imp,
                                                     const float* __restrict__ invSumP,
                                                     int bstart) {
  int brel = blockIdx.y;
  int b = bstart + brel;
  int wid = threadIdx.x >> 6;
  int lane = threadIdx.x & 63;
  int i = blockIdx.x * 4 + wid;
  float* row = A + ((size_t)brel * KN + i) * KN;
  __shared__ float im[KN];
  ((float4*)im)[threadIdx.x] = ((const float4*)(imp + (size_t)b * KN))[threadIdx.x];
  __syncthreads();

  float4 v[4];
  unsigned key[16];
#pragma unroll
  for (int q = 0; q < 4; ++q) v[q] = ((const float4*)row)[lane + 64 * q];
#pragma unroll
  for (int q = 0; q < 4; ++q) {
    const float* pv = (const float*)&v[q];
#pragma unroll
    for (int e = 0; e < 4; ++e) {
      unsigned u = __float_as_uint(pv[e]);
      key[q * 4 + e] = (u & 0x80000000u) ? ~u : (u | 0x80000000u);
    }
  }
  unsigned tk = 0u;
#pragma unroll 1
  for (int bit = 31; bit >= 0; --bit) {
    unsigned cand = tk | (1u << bit);
    int c = 0;
#pragma unroll
    for (int e = 0; e < 16; ++e) c += (key[e] >= cand) ? 1 : 0;
#pragma unroll
    for (int off = 32; off > 0; off >>= 1) c += __shfl_xor(c, off);
    if (c >= ADJ_KK) tk = cand;
  }
  float m[16];
  float s = 0.0f;
#pragma unroll
  for (int q = 0; q < 4; ++q) {
    const float* pv = (const float*)&v[q];
#pragma unroll
    for (int e = 0; e < 4; ++e) {
      float mv = (key[q * 4 + e] >= tk) ? pv[e] : 0.0f;
      m[q * 4 + e] = mv;
      s += mv;
    }
  }
#pragma unroll
  for (int off = 32; off > 0; off >>= 1) s += __shfl_xor(s, off);
  float invF = 1.0f / (s + 1.0f + EPSF);
  float vi = im[i];
  float invP = invSumP[(size_t)b * KN + i];
  ushort* rowb = (ushort*)row;
#pragma unroll
  for (int q = 0; q < 4; ++q) {
    float4 iv = ((const float4*)im)[lane + 64 * q];
    const float* ip = (const float*)&iv;
    ushort4 r;
    ushort* rp = (ushort*)&r;
    int colb = 4 * lane + 256 * q;
#pragma unroll
    for (int e = 0; e < 4; ++e) {
      float diag = (colb + e == i) ? 1.0f : 0.0f;
      float d = vi - ip[e];
      rp[e] = f2bf((m[q * 4 + e] + diag) * invF + (__expf(-d * d * 0.125f) + diag) * invP);
    }
    ((ushort4*)rowb)[lane + 64 * q] = r;
  }
}

// ------- bf16 transpose: At[b][j][k] = A[b][k][j] (A row stride 2048) ----
__global__ void at_kernel(const float* __restrict__ Asim, ushort* __restrict__ At) {
  int brel = blockIdx.z;
  int k0 = blockIdx.x * 64;
  int j0 = blockIdx.y * 64;
  __shared__ ushort t[64][65];
  const ushort* Ab = (const ushort*)(Asim + (size_t)brel * KN * KN);
  int tx = threadIdx.x & 63;
  int ty = threadIdx.x >> 6;
  for (int r = 0; r < 64; r += 4) t[r + ty][tx] = Ab[(size_t)(k0 + r + ty) * 2048 + j0 + tx];
  __syncthreads();
  ushort* ob = At + (size_t)brel * KN * KN;
  for (int r = 0; r < 64; r += 4) ob[(size_t)(j0 + r + ty) * KN + k0 + tx] = t[tx][r + ty];
}

// ---------------- per-node linear: h[b,o,k] = sum_c f[b,c,k] W[c,o] (bf16 out)
// o-tile = 8: 16KB LDS Ws tile, grid (M/8)*32 (2 blk/CU), b-major flat grid
// (stride 32 = 0 mod 8) keeps batch b's blocks on one XCD sharing x[b] in L2.
template <int C, int M, bool MASK>
__global__ __launch_bounds__(256) void linear_kernel(const float* __restrict__ f,
                                                     const float* __restrict__ W,
                                                     ushort* __restrict__ outp,
                                                     const float* __restrict__ mTK) {
  int fl = blockIdx.x;
  int b = fl & 31;
  int o0 = (fl >> 5) * 8;
  __shared__ float Ws[C][8];
  for (int l = threadIdx.x; l < C * 8; l += 256) {
    int c = l >> 3, o = l & 7;
    Ws[c][o] = W[(size_t)c * M + o0 + o];
  }
  __syncthreads();
  int k0 = threadIdx.x * 4;
  const float* fb = f + (size_t)b * C * KN;
  float acc[8][4] = {};
  for (int c = 0; c < C; ++c) {
    float4 xv = *(const float4*)(fb + (size_t)c * KN + k0);
#pragma unroll
    for (int o = 0; o < 8; ++o) {
      float w = Ws[c][o];
      acc[o][0] += xv.x * w;
      acc[o][1] += xv.y * w;
      acc[o][2] += xv.z * w;
      acc[o][3] += xv.w * w;
    }
  }
  float ms[4] = {1.0f, 1.0f, 1.0f, 1.0f};
  if (MASK) {
#pragma unroll
    for (int jj = 0; jj < 4; ++jj) ms[jj] = mTK[(size_t)b * KN + k0 + jj] * INV_DS;
  }
#pragma unroll
  for (int o = 0; o < 8; ++o) {
    ushort4 r;
    r.x = f2bf(acc[o][0] * ms[0]);
    r.y = f2bf(acc[o][1] * ms[1]);
    r.z = f2bf(acc[o][2] * ms[2]);
    r.w = f2bf(acc[o][3] * ms[3]);
    *(ushort4*)(outp + ((size_t)b * M + o0 + o) * KN + k0) = r;
  }
}

// ---------------- MFMA s = relu(h @ A) via At, LDS-staged ----------------
template <int M>
__global__ __launch_bounds__(256) void sgemmf_kernel(const ushort* __restrict__ hB,
                                                     const ushort* __restrict__ At,
                                                     float* __restrict__ outp, int bstart) {
  int brel = blockIdx.z;
  int b = bstart + brel;
  int t = threadIdx.x;
  int lane = t & 63;
  int wid = t >> 6;
  int iB = blockIdx.y * 64;
  int jB = blockIdx.x * 128;
  const ushort* hb = hB + (size_t)b * M * KN;
  const ushort* Ab = At + (size_t)brel * KN * KN;

  __shared__ ushort Hs[2][64 * 32];
  __shared__ ushort Bs[2][128 * 32];
  __shared__ float ep[4][16][65];

  int srow = t >> 2;
  int scol = (t & 3) * 8;
  int ldst = t * 8;

  auto stage = [&](int buf, int k0) {
    gll16(hb + (size_t)(iB + srow) * KN + k0 + scol, &Hs[buf][ldst]);
    gll16(Ab + (size_t)(jB + srow) * KN + k0 + scol, &Bs[buf][ldst]);
    gll16(Ab + (size_t)(jB + 64 + srow) * KN + k0 + scol, &Bs[buf][2048 + ldst]);
  };

  int i0loc = (wid >> 1) * 32;
  int j0loc = (wid & 1) * 64;
  int r = lane & 15;
  int s = (lane >> 4) * 8;

  f32x4 acc[2][4] = {};
  stage(0, 0);
  __syncthreads();
  int cur = 0;
#pragma unroll 2
  for (int ks = 0; ks < KN / 32; ++ks) {
    if (ks + 1 < KN / 32) stage(cur ^ 1, (ks + 1) * 32);
    bf16x8 a[2], bb[4];
#pragma unroll
    for (int m = 0; m < 2; ++m)
      a[m] = *reinterpret_cast<const bf16x8*>(&Hs[cur][(i0loc + m * 16 + r) * 32 + s]);
#pragma unroll
    for (int n = 0; n < 4; ++n)
      bb[n] = *reinterpret_cast<const bf16x8*>(&Bs[cur][(j0loc + n * 16 + r) * 32 + s]);
#pragma unroll
    for (int m = 0; m < 2; ++m)
#pragma unroll
      for (int n = 0; n < 4; ++n)
        acc[m][n] = __builtin_amdgcn_mfma_f32_16x16x32_bf16(a[m], bb[n], acc[m][n], 0, 0, 0);
    __syncthreads();
    cur ^= 1;
  }

  float(*buf)[65] = ep[wid];
  int orow = (lane >> 4) * 4;
  int ocol = lane & 15;
  int i0 = iB + i0loc;
  int j0 = jB + j0loc;
  float* ob = outp + (size_t)b * M * KN;
#pragma unroll
  for (int m = 0; m < 2; ++m) {
#pragma unroll
    for (int n = 0; n < 4; ++n)
#pragma unroll
      for (int rr = 0; rr < 4; ++rr) buf[orow + rr][n * 16 + ocol] = fmaxf(acc[m][n][rr], 0.0f);
#pragma unroll
    for (int rr = 0; rr < 4; ++rr) {
      int row = rr * 4 + (lane >> 4);
      float4 v4 = *(const float4*)&buf[row][(lane & 15) * 4];
      *(float4*)(ob + (size_t)(i0 + m * 16 + row) * KN + j0 + (lane & 15) * 4) = v4;
    }
  }
}

// ---------------- reductions ---------------------------------------------
__global__ void bag12_kernel(const float* __restrict__ emb1, const float* __restrict__ mTK,
                             const float* __restrict__ mTD, const float* __restrict__ imp,
                             float* __restrict__ bagk, float* __restrict__ bagd) {
  int c = blockIdx.x, b = blockIdx.y;
  int t = threadIdx.x;
  const float* e = emb1 + ((size_t)b * CMID + c) * KN;
  const float* ir = imp + (size_t)b * KN;
  const float* m1 = mTK + (size_t)b * KN;
  const float* m2 = mTD + (size_t)b * KN;
  float s1 = 0.0f, sd = 0.0f;
  for (int k = t; k < KN; k += 256) {
    float ev = e[k] * ir[k];
    s1 += ev * m1[k];
    sd += ev * m2[k];
  }
  __shared__ float r1[256], r2[256];
  r1[t] = s1;
  r2[t] = sd;
  __syncthreads();
  for (int st = 128; st > 0; st >>= 1) {
    if (t < st) {
      r1[t] += r1[t + st];
      r2[t] += r2[t + st];
    }
    __syncthreads();
  }
  if (t == 0) {
    bagk[(size_t)b * CMID + c] = r1[0] * INV_DS;
    bagd[(size_t)b * CMID + c] = r2[0] * INV_DS;
  }
}

__global__ void bag2_kernel(const float* __restrict__ s2, const float* __restrict__ mTK,
                            const float* __restrict__ imp, float* __restrict__ bag) {
  int o = blockIdx.x, b = blockIdx.y;
  int t = threadIdx.x;
  const float* sr = s2 + ((size_t)b * COUT + o) * KN;
  const float* ir = imp + (size_t)b * KN;
  const float* mr = mTK + (size_t)b * KN;
  float s = 0.0f;
  for (int k = t; k < KN; k += 256) s += sr[k] * mr[k] * ir[k];
  __shared__ float red[256];
  red[t] = s;
  __syncthreads();
  for (int st = 128; st > 0; st >>= 1) {
    if (t < st) red[t] += red[t + st];
    __syncthreads();
  }
  if (t == 0) bag[(size_t)b * COUT + o] = red[0];
}

__global__ void pooled_kernel(const float* __restrict__ x, const float* __restrict__ imp,
                              float* __restrict__ pooled) {
  int c = blockIdx.x, b = blockIdx.y;
  int t = threadIdx.x;
  const float* xr = x + ((size_t)b * CIN + c) * KN;
  const float* ir = imp + (size_t)b * KN;
  float s = 0.0f;
  for (int k = t; k < KN; k += 256) s += xr[k] * ir[k];
  __shared__ float red[256];
  red[t] = s;
  __syncthreads();
  for (int st = 128; st > 0; st >>= 1) {
    if (t < st) red[t] += red[t + st];
    __syncthreads();
  }
  if (t == 0) pooled[(size_t)b * CIN + c] = red[0];
}

__global__ void final_kernel(const float* __restrict__ pooled, const float* __restrict__ bag,
                             const float* __restrict__ id_w, const float* __restrict__ id_b,
                             const float* __restrict__ fc_w, float* __restrict__ out) {
  int b = blockIdx.x;
  int o = threadIdx.x;
  __shared__ float v[COUT];
  float s = id_b[o];
  const float* pr = pooled + (size_t)b * CIN;
  for (int c = 0; c < CIN; ++c) s += pr[c] * id_w[(size_t)c * COUT + o];
  v[o] = bag[(size_t)b * COUT + o] + fmaxf(s, 0.0f);
  __syncthreads();
  if (o < NCLS) {
    float acc = 0.0f;
    for (int oo = 0; oo < COUT; ++oo) acc += v[oo] * fc_w[(size_t)oo * NCLS + o];
    out[(size_t)b * NCLS + o] = acc;
  }
}

// ---------------- launch --------------------------------------------------
extern "C" void kernel_launch(void* const* d_in, const int* in_sizes, int n_in,
                              void* d_out, int out_size, void* d_ws, size_t ws_size,
                              hipStream_t stream) {
  const float* x = (const float*)d_in[0];
  const float* imp = (const float*)d_in[1];
  const float* rnd = (const float*)d_in[2];
  const float* W1 = (const float*)d_in[3];
  const float* W2 = (const float*)d_in[4];
  const float* fc_w = (const float*)d_in[5];
  const float* id_w = (const float*)d_in[6];
  const float* id_b = (const float*)d_in[7];
  float* out = (float*)d_out;
  float* emb1 = out + BN_ * NCLS;
  float* bagk = emb1 + (size_t)BN_ * CMID * KN;
  float* bagd = bagk + (size_t)BN_ * CMID;

  float* w = (float*)d_ws;
  size_t off = 0;
  auto take = [&](size_t n) {
    float* p = w + off;
    off += n;
    return p;
  };
  float* invSumP = take((size_t)BN_ * KN);
  float* invNX = take((size_t)BN_ * KN);
  float* invNE = take((size_t)BN_ * KN);
  float* topM = take((size_t)BN_ * KN);
  float* mTK = take((size_t)BN_ * KN);
  float* mTD = take((size_t)BN_ * KN);
  ushort* h = (ushort*)take((size_t)BN_ * CMID * KN / 2);
  ushort* h2 = (ushort*)take((size_t)BN_ * COUT * KN / 2);
  float* s2 = take((size_t)BN_ * COUT * KN);
  float* bag = take((size_t)BN_ * COUT);
  float* pooled = take((size_t)BN_ * CIN);
  ushort* xnT = (ushort*)take((size_t)BN_ * CIN * KN / 2);
  ushort* enT = (ushort*)take((size_t)BN_ * CMID * KN / 2);
  long long avail = (long long)(ws_size / 4) - (long long)off;
  int nb = 1;
  const int cands[6] = {32, 16, 8, 4, 2, 1};
  for (int ci = 0; ci < 6; ++ci) {
    if ((long long)cands[ci] * KN * KN * 3 / 2 <= avail) {
      nb = cands[ci];
      break;
    }
  }
  float* simA = take((size_t)nb * KN * KN);
  ushort* At = (ushort*)take((size_t)nb * KN * KN / 2);

  masks1_kernel<<<dim3(KN / 256, BN_), 256, 0, stream>>>(imp, topM);
  masks2_kernel<<<dim3(KN / 256, BN_), 256, 0, stream>>>(rnd, topM, mTK, mTD);
  psum_kernel<<<dim3(KN / 256, BN_), 256, 0, stream>>>(imp, invSumP);
  colnorm_kernel<CIN><<<(BN_ * KN) / 256, 256, 0, stream>>>(x, invNX);
  xpose_kernel<CIN><<<dim3(KN / 64, CIN / 64, BN_), 256, 0, stream>>>(x, invNX,
                                                                      (__hip_bfloat16*)xnT);
  linear_kernel<CIN, CMID, false><<<(CMID / 8) * BN_, 256, 0, stream>>>(x, W1, h, nullptr);

  for (int bs = 0; bs < BN_; bs += nb) {
    simf_kernel<CIN><<<nb * 64, 256, 0, stream>>>(xnT, simA, bs, nb);
    thrfin_kernel<<<dim3(KN / 4, nb), 256, 0, stream>>>(simA, imp, invSumP, bs);
    at_kernel<<<dim3(KN / 64, KN / 64, nb), 256, 0, stream>>>(simA, At);
    sgemmf_kernel<CMID><<<dim3(KN / 128, CMID / 64, nb), 256, 0, stream>>>(h, At, emb1, bs);
  }

  colnorm_kernel<CMID><<<(BN_ * KN) / 256, 256, 0, stream>>>(emb1, invNE);
  xpose_kernel<CMID><<<dim3(KN / 64, CMID / 64, BN_), 256, 0, stream>>>(emb1, invNE,
                                                                        (__hip_bfloat16*)enT);
  linear_kernel<CMID, COUT, true><<<(COUT / 8) * BN_, 256, 0, stream>>>(emb1, W2, h2, mTK);

  for (int bs = 0; bs < BN_; bs += nb) {
    simf_kernel<CMID><<<nb * 64, 256, 0, stream>>>(enT, simA, bs, nb);
    thrfin_kernel<<<dim3(KN / 4, nb), 256, 0, stream>>>(simA, imp, invSumP, bs);
    at_kernel<<<dim3(KN / 64, KN / 64, nb), 256, 0, stream>>>(simA, At);
    sgemmf_kernel<COUT><<<dim3(KN / 128, COUT / 64, nb), 256, 0, stream>>>(h2, At, s2, bs);
  }

  bag12_kernel<<<dim3(CMID, BN_), 256, 0, stream>>>(emb1, mTK, mTD, imp, bagk, bagd);
  bag2_kernel<<<dim3(COUT, BN_), 256, 0, stream>>>(s2, mTK, imp, bag);
  pooled_kernel<<<dim3(CIN, BN_), 256, 0, stream>>>(x, imp, pooled);
  final_kernel<<<BN_, 64, 0, stream>>>(pooled, bag, id_w, id_b, fc_w, out);
}

// Round 13
// 651.645 us; speedup vs baseline: 1.1153x; 1.0232x over previous
//
#include <hip/hip_runtime.h>
#include <hip/hip_bf16.h>
#include <math.h>

#define BN_ 32
#define CIN 512
#define KN 1024
#define CMID 128
#define COUT 64
#define NCLS 5
#define NUM_TOP 205
#define NUM_KEPT 409
#define NUM_DROP 410
#define ADJ_KK 204
#define EPSF 1e-8f
#define INV_DS (1.0f / 0.599609375f)

typedef __bf16 bf16x8 __attribute__((ext_vector_type(8)));
typedef float f32x4 __attribute__((ext_vector_type(4)));

__device__ inline ushort f2bf(float x) {
  union { __hip_bfloat16 b; ushort u; } c;
  c.b = __float2bfloat16(x);
  return c.u;
}

// async global->LDS, 16B per lane (dest = wave-uniform base + lane*16)
__device__ inline void gll16(const ushort* g, ushort* l) {
  __builtin_amdgcn_global_load_lds(
      (const __attribute__((address_space(1))) unsigned int*)g,
      (__attribute__((address_space(3))) unsigned int*)l, 16, 0, 0);
}

// ---------------- masks stage 1: top mask via rank counting --------------
__global__ __launch_bounds__(256) void masks1_kernel(const float* __restrict__ imp,
                                                     float* __restrict__ topM) {
  int b = blockIdx.y;
  int i = blockIdx.x * 256 + threadIdx.x;
  __shared__ float im[KN];
  for (int j = threadIdx.x; j < KN; j += 256) im[j] = imp[(size_t)b * KN + j];
  __syncthreads();
  float vi = im[i];
  int r0 = 0, r1 = 0, r2 = 0, r3 = 0;
  for (int j = 0; j < KN; j += 4) {
    float a0 = im[j], a1 = im[j + 1], a2 = im[j + 2], a3 = im[j + 3];
    r0 += (a0 > vi || (a0 == vi && j < i)) ? 1 : 0;
    r1 += (a1 > vi || (a1 == vi && j + 1 < i)) ? 1 : 0;
    r2 += (a2 > vi || (a2 == vi && j + 2 < i)) ? 1 : 0;
    r3 += (a3 > vi || (a3 == vi && j + 3 < i)) ? 1 : 0;
  }
  int rank = r0 + r1 + r2 + r3;
  topM[(size_t)b * KN + i] = (rank < NUM_TOP) ? 1.0f : 0.0f;
}

// ---------------- masks stage 2: kept/drop ranks, fused ------------------
__global__ __launch_bounds__(256) void masks2_kernel(const float* __restrict__ rnd,
                                                     const float* __restrict__ topM,
                                                     float* __restrict__ mTK,
                                                     float* __restrict__ mTD) {
  int b = blockIdx.y;
  int i = blockIdx.x * 256 + threadIdx.x;
  __shared__ float r1s[KN];
  __shared__ float r2s[KN];
  for (int j = threadIdx.x; j < KN; j += 256) {
    float tv = topM[(size_t)b * KN + j];
    float rv = rnd[(size_t)b * KN + j];
    r1s[j] = (tv > 0.5f) ? -10.0f : rv;
    r2s[j] = (tv > 0.5f) ? 10.0f : rv;
  }
  __syncthreads();
  float v1 = r1s[i];
  float v2 = r2s[i];
  int c1a = 0, c1b = 0, c2a = 0, c2b = 0;
  for (int j = 0; j < KN; j += 2) {
    float a0 = r1s[j], a1 = r1s[j + 1];
    float b0 = r2s[j], b1 = r2s[j + 1];
    c1a += (a0 > v1 || (a0 == v1 && j < i)) ? 1 : 0;
    c1b += (a1 > v1 || (a1 == v1 && j + 1 < i)) ? 1 : 0;
    c2a += (b0 < v2 || (b0 == v2 && j < i)) ? 1 : 0;
    c2b += (b1 < v2 || (b1 == v2 && j + 1 < i)) ? 1 : 0;
  }
  int kept = (c1a + c1b) < NUM_KEPT;
  int drop = (c2a + c2b) < NUM_DROP;
  int top = topM[(size_t)b * KN + i] > 0.5f;
  mTK[(size_t)b * KN + i] = (top || kept) ? 1.0f : 0.0f;
  mTD[(size_t)b * KN + i] = (top || drop) ? 1.0f : 0.0f;
}

// ---------------- adjP row-sum reciprocals -------------------------------
__global__ void psum_kernel(const float* __restrict__ imp, float* __restrict__ invSumP) {
  int b = blockIdx.y;
  int i = blockIdx.x * 256 + threadIdx.x;
  __shared__ float im[KN];
  for (int j = threadIdx.x; j < KN; j += 256) im[j] = imp[(size_t)b * KN + j];
  __syncthreads();
  float vi = im[i];
  float s = 0.0f;
  for (int j = 0; j < KN; ++j) {
    float d = vi - im[j];
    s += __expf(-d * d * 0.125f);
  }
  invSumP[(size_t)b * KN + i] = 1.0f / (s + 1.0f + EPSF);
}

// ---------------- per-column L2 norm reciprocals -------------------------
template <int C>
__global__ void colnorm_kernel(const float* __restrict__ f, float* __restrict__ inv) {
  int idx = blockIdx.x * 256 + threadIdx.x;
  int b = idx >> 10;
  int k = idx & (KN - 1);
  const float* fb = f + (size_t)b * C * KN + k;
  float ss = 0.0f;
  for (int c = 0; c < C; ++c) {
    float v = fb[(size_t)c * KN];
    ss += v * v;
  }
  inv[idx] = 1.0f / (sqrtf(ss) + EPSF);
}

// ------- transpose + normalize + bf16: oT[b][k][c] = f[b][c][k]*inv[b][k] --
template <int C>
__global__ void xpose_kernel(const float* __restrict__ f, const float* __restrict__ inv,
                             __hip_bfloat16* __restrict__ oT) {
  int b = blockIdx.z;
  int k0 = blockIdx.x * 64;
  int c0 = blockIdx.y * 64;
  __shared__ float t[64][65];
  const float* fb = f + (size_t)b * C * KN;
  int tx = threadIdx.x & 63;
  int ty = threadIdx.x >> 6;
  for (int r = 0; r < 64; r += 4) t[r + ty][tx] = fb[(size_t)(c0 + r + ty) * KN + k0 + tx];
  __syncthreads();
  __hip_bfloat16* ob = oT + (size_t)b * KN * C;
  for (int r = 0; r < 64; r += 4) {
    int k = r + ty;
    float s = inv[(size_t)b * KN + k0 + k];
    ob[(size_t)(k0 + k) * C + c0 + tx] = __float2bfloat16(t[tx][k] * s);
  }
}

// ---------------- MFMA sim: sim = XnT * XnT^T (Gram, symmetric) ----------
template <int C>
__global__ __launch_bounds__(256) void simf_kernel(const ushort* __restrict__ xT,
                                                   float* __restrict__ sim, int bstart, int nb) {
  int f = blockIdx.x;
  int brel, tile;
  if ((nb & 7) == 0) {
    int xcd = f & 7;
    int wdx = f >> 3;
    brel = xcd * (nb >> 3) + (wdx >> 6);
    tile = wdx & 63;
  } else {
    brel = f >> 6;
    tile = f & 63;
  }
  int b = bstart + brel;
  int t = threadIdx.x;
  int lane = t & 63;
  int wid = t >> 6;
  int iB = (tile >> 3) * 128;
  int jB = (tile & 7) * 128;
  const ushort* X = xT + (size_t)b * KN * C;

  __shared__ ushort As[2][128 * 32];
  __shared__ ushort Bs[2][128 * 32];
  __shared__ float ep[4][16][65];

  int srow = t >> 2;
  int scol = (t & 3) * 8;
  int ldst = t * 8;

  auto stage = [&](int buf, int c0) {
    gll16(X + (size_t)(iB + srow) * C + c0 + scol, &As[buf][ldst]);
    gll16(X + (size_t)(iB + 64 + srow) * C + c0 + scol, &As[buf][2048 + ldst]);
    gll16(X + (size_t)(jB + srow) * C + c0 + scol, &Bs[buf][ldst]);
    gll16(X + (size_t)(jB + 64 + srow) * C + c0 + scol, &Bs[buf][2048 + ldst]);
  };

  int i0loc = (wid >> 1) * 64;
  int j0loc = (wid & 1) * 64;
  int r = lane & 15;
  int s = (lane >> 4) * 8;

  f32x4 acc[4][4] = {};
  stage(0, 0);
  __syncthreads();
  constexpr int NT = C / 32;
  int cur = 0;
#pragma unroll 2
  for (int ks = 0; ks < NT; ++ks) {
    if (ks + 1 < NT) stage(cur ^ 1, (ks + 1) * 32);
    bf16x8 a[4], bb[4];
#pragma unroll
    for (int m = 0; m < 4; ++m)
      a[m] = *reinterpret_cast<const bf16x8*>(&As[cur][(i0loc + m * 16 + r) * 32 + s]);
#pragma unroll
    for (int n = 0; n < 4; ++n)
      bb[n] = *reinterpret_cast<const bf16x8*>(&Bs[cur][(j0loc + n * 16 + r) * 32 + s]);
#pragma unroll
    for (int m = 0; m < 4; ++m)
#pragma unroll
      for (int n = 0; n < 4; ++n)
        acc[m][n] = __builtin_amdgcn_mfma_f32_16x16x32_bf16(a[m], bb[n], acc[m][n], 0, 0, 0);
    __syncthreads();
    cur ^= 1;
  }

  float(*buf)[65] = ep[wid];
  int orow = (lane >> 4) * 4;
  int ocol = lane & 15;
  int i0 = iB + i0loc;
  int j0 = jB + j0loc;
  float* simb = sim + (size_t)brel * KN * KN;
#pragma unroll
  for (int m = 0; m < 4; ++m) {
#pragma unroll
    for (int n = 0; n < 4; ++n)
#pragma unroll
      for (int rr = 0; rr < 4; ++rr) buf[orow + rr][n * 16 + ocol] = acc[m][n][rr];
#pragma unroll
    for (int rr = 0; rr < 4; ++rr) {
      int row = rr * 4 + (lane >> 4);
      float4 v4 = *(const float4*)&buf[row][(lane & 15) * 4];
      *(float4*)(simb + (size_t)(i0 + m * 16 + row) * KN + j0 + (lane & 15) * 4) = v4;
    }
  }
}

// ------- fused per-wave threshold select + finalize ----------------------
// Bisection count via ballot + scalar popcount: per step 16 v_cmp on the
// VALU, popcount+accumulate on the SALU (parallel pipes), no DS shuffles.
__global__ __launch_bounds__(256) void thrfin_kernel(float* __restrict__ A,
                                                     const float* __restrict__ imp,
                                                     const float* __restrict__ invSumP,
                                                     int bstart) {
  int brel = blockIdx.y;
  int b = bstart + brel;
  int wid = threadIdx.x >> 6;
  int lane = threadIdx.x & 63;
  int i = blockIdx.x * 4 + wid;
  float* row = A + ((size_t)brel * KN + i) * KN;
  __shared__ float im[KN];
  ((float4*)im)[threadIdx.x] = ((const float4*)(imp + (size_t)b * KN))[threadIdx.x];
  __syncthreads();

  float4 v[4];
  unsigned key[16];
#pragma unroll
  for (int q = 0; q < 4; ++q) v[q] = ((const float4*)row)[lane + 64 * q];
#pragma unroll
  for (int q = 0; q < 4; ++q) {
    const float* pv = (const float*)&v[q];
#pragma unroll
    for (int e = 0; e < 4; ++e) {
      unsigned u = __float_as_uint(pv[e]);
      key[q * 4 + e] = (u & 0x80000000u) ? ~u : (u | 0x80000000u);
    }
  }
  unsigned tk = 0u;
#pragma unroll 1
  for (int bit = 31; bit >= 0; --bit) {
    unsigned cand = tk | (1u << bit);
    int c = 0;
#pragma unroll
    for (int e = 0; e < 16; ++e)
      c += (int)__popcll(__ballot(key[e] >= cand));
    if (c >= ADJ_KK) tk = cand;
  }
  float m[16];
  float s = 0.0f;
#pragma unroll
  for (int q = 0; q < 4; ++q) {
    const float* pv = (const float*)&v[q];
#pragma unroll
    for (int e = 0; e < 4; ++e) {
      float mv = (key[q * 4 + e] >= tk) ? pv[e] : 0.0f;
      m[q * 4 + e] = mv;
      s += mv;
    }
  }
#pragma unroll
  for (int off = 32; off > 0; off >>= 1) s += __shfl_xor(s, off);
  float invF = 1.0f / (s + 1.0f + EPSF);
  float vi = im[i];
  float invP = invSumP[(size_t)b * KN + i];
  ushort* rowb = (ushort*)row;
#pragma unroll
  for (int q = 0; q < 4; ++q) {
    float4 iv = ((const float4*)im)[lane + 64 * q];
    const float* ip = (const float*)&iv;
    ushort4 r;
    ushort* rp = (ushort*)&r;
    int colb = 4 * lane + 256 * q;
#pragma unroll
    for (int e = 0; e < 4; ++e) {
      float diag = (colb + e == i) ? 1.0f : 0.0f;
      float d = vi - ip[e];
      rp[e] = f2bf((m[q * 4 + e] + diag) * invF + (__expf(-d * d * 0.125f) + diag) * invP);
    }
    ((ushort4*)rowb)[lane + 64 * q] = r;
  }
}

// ------- bf16 transpose: At[b][j][k] = A[b][k][j] (A row stride 2048) ----
__global__ void at_kernel(const float* __restrict__ Asim, ushort* __restrict__ At) {
  int brel = blockIdx.z;
  int k0 = blockIdx.x * 64;
  int j0 = blockIdx.y * 64;
  __shared__ ushort t[64][65];
  const ushort* Ab = (const ushort*)(Asim + (size_t)brel * KN * KN);
  int tx = threadIdx.x & 63;
  int ty = threadIdx.x >> 6;
  for (int r = 0; r < 64; r += 4) t[r + ty][tx] = Ab[(size_t)(k0 + r + ty) * 2048 + j0 + tx];
  __syncthreads();
  ushort* ob = At + (size_t)brel * KN * KN;
  for (int r = 0; r < 64; r += 4) ob[(size_t)(j0 + r + ty) * KN + k0 + tx] = t[tx][r + ty];
}

// ---------------- per-node linear: h[b,o,k] = sum_c f[b,c,k] W[c,o] (bf16 out)
// o-tile = 8: 16KB LDS Ws tile, grid (M/8)*32 (2 blk/CU), b-major flat grid
// (stride 32 = 0 mod 8) keeps batch b's blocks on one XCD sharing x[b] in L2.
template <int C, int M, bool MASK>
__global__ __launch_bounds__(256) void linear_kernel(const float* __restrict__ f,
                                                     const float* __restrict__ W,
                                                     ushort* __restrict__ outp,
                                                     const float* __restrict__ mTK) {
  int fl = blockIdx.x;
  int b = fl & 31;
  int o0 = (fl >> 5) * 8;
  __shared__ float Ws[C][8];
  for (int l = threadIdx.x; l < C * 8; l += 256) {
    int c = l >> 3, o = l & 7;
    Ws[c][o] = W[(size_t)c * M + o0 + o];
  }
  __syncthreads();
  int k0 = threadIdx.x * 4;
  const float* fb = f + (size_t)b * C * KN;
  float acc[8][4] = {};
  for (int c = 0; c < C; ++c) {
    float4 xv = *(const float4*)(fb + (size_t)c * KN + k0);
#pragma unroll
    for (int o = 0; o < 8; ++o) {
      float w = Ws[c][o];
      acc[o][0] += xv.x * w;
      acc[o][1] += xv.y * w;
      acc[o][2] += xv.z * w;
      acc[o][3] += xv.w * w;
    }
  }
  float ms[4] = {1.0f, 1.0f, 1.0f, 1.0f};
  if (MASK) {
#pragma unroll
    for (int jj = 0; jj < 4; ++jj) ms[jj] = mTK[(size_t)b * KN + k0 + jj] * INV_DS;
  }
#pragma unroll
  for (int o = 0; o < 8; ++o) {
    ushort4 r;
    r.x = f2bf(acc[o][0] * ms[0]);
    r.y = f2bf(acc[o][1] * ms[1]);
    r.z = f2bf(acc[o][2] * ms[2]);
    r.w = f2bf(acc[o][3] * ms[3]);
    *(ushort4*)(outp + ((size_t)b * M + o0 + o) * KN + k0) = r;
  }
}

// ---------------- MFMA s = relu(h @ A) via At, LDS-staged ----------------
template <int M>
__global__ __launch_bounds__(256) void sgemmf_kernel(const ushort* __restrict__ hB,
                                                     const ushort* __restrict__ At,
                                                     float* __restrict__ outp, int bstart) {
  int brel = blockIdx.z;
  int b = bstart + brel;
  int t = threadIdx.x;
  int lane = t & 63;
  int wid = t >> 6;
  int iB = blockIdx.y * 64;
  int jB = blockIdx.x * 128;
  const ushort* hb = hB + (size_t)b * M * KN;
  const ushort* Ab = At + (size_t)brel * KN * KN;

  __shared__ ushort Hs[2][64 * 32];
  __shared__ ushort Bs[2][128 * 32];
  __shared__ float ep[4][16][65];

  int srow = t >> 2;
  int scol = (t & 3) * 8;
  int ldst = t * 8;

  auto stage = [&](int buf, int k0) {
    gll16(hb + (size_t)(iB + srow) * KN + k0 + scol, &Hs[buf][ldst]);
    gll16(Ab + (size_t)(jB + srow) * KN + k0 + scol, &Bs[buf][ldst]);
    gll16(Ab + (size_t)(jB + 64 + srow) * KN + k0 + scol, &Bs[buf][2048 + ldst]);
  };

  int i0loc = (wid >> 1) * 32;
  int j0loc = (wid & 1) * 64;
  int r = lane & 15;
  int s = (lane >> 4) * 8;

  f32x4 acc[2][4] = {};
  stage(0, 0);
  __syncthreads();
  int cur = 0;
#pragma unroll 2
  for (int ks = 0; ks < KN / 32; ++ks) {
    if (ks + 1 < KN / 32) stage(cur ^ 1, (ks + 1) * 32);
    bf16x8 a[2], bb[4];
#pragma unroll
    for (int m = 0; m < 2; ++m)
      a[m] = *reinterpret_cast<const bf16x8*>(&Hs[cur][(i0loc + m * 16 + r) * 32 + s]);
#pragma unroll
    for (int n = 0; n < 4; ++n)
      bb[n] = *reinterpret_cast<const bf16x8*>(&Bs[cur][(j0loc + n * 16 + r) * 32 + s]);
#pragma unroll
    for (int m = 0; m < 2; ++m)
#pragma unroll
      for (int n = 0; n < 4; ++n)
        acc[m][n] = __builtin_amdgcn_mfma_f32_16x16x32_bf16(a[m], bb[n], acc[m][n], 0, 0, 0);
    __syncthreads();
    cur ^= 1;
  }

  float(*buf)[65] = ep[wid];
  int orow = (lane >> 4) * 4;
  int ocol = lane & 15;
  int i0 = iB + i0loc;
  int j0 = jB + j0loc;
  float* ob = outp + (size_t)b * M * KN;
#pragma unroll
  for (int m = 0; m < 2; ++m) {
#pragma unroll
    for (int n = 0; n < 4; ++n)
#pragma unroll
      for (int rr = 0; rr < 4; ++rr) buf[orow + rr][n * 16 + ocol] = fmaxf(acc[m][n][rr], 0.0f);
#pragma unroll
    for (int rr = 0; rr < 4; ++rr) {
      int row = rr * 4 + (lane >> 4);
      float4 v4 = *(const float4*)&buf[row][(lane & 15) * 4];
      *(float4*)(ob + (size_t)(i0 + m * 16 + row) * KN + j0 + (lane & 15) * 4) = v4;
    }
  }
}

// ---------------- reductions ---------------------------------------------
__global__ void bag12_kernel(const float* __restrict__ emb1, const float* __restrict__ mTK,
                             const float* __restrict__ mTD, const float* __restrict__ imp,
                             float* __restrict__ bagk, float* __restrict__ bagd) {
  int c = blockIdx.x, b = blockIdx.y;
  int t = threadIdx.x;
  const float* e = emb1 + ((size_t)b * CMID + c) * KN;
  const float* ir = imp + (size_t)b * KN;
  const float* m1 = mTK + (size_t)b * KN;
  const float* m2 = mTD + (size_t)b * KN;
  float s1 = 0.0f, sd = 0.0f;
  for (int k = t; k < KN; k += 256) {
    float ev = e[k] * ir[k];
    s1 += ev * m1[k];
    sd += ev * m2[k];
  }
  __shared__ float r1[256], r2[256];
  r1[t] = s1;
  r2[t] = sd;
  __syncthreads();
  for (int st = 128; st > 0; st >>= 1) {
    if (t < st) {
      r1[t] += r1[t + st];
      r2[t] += r2[t + st];
    }
    __syncthreads();
  }
  if (t == 0) {
    bagk[(size_t)b * CMID + c] = r1[0] * INV_DS;
    bagd[(size_t)b * CMID + c] = r2[0] * INV_DS;
  }
}

__global__ void bag2_kernel(const float* __restrict__ s2, const float* __restrict__ mTK,
                            const float* __restrict__ imp, float* __restrict__ bag) {
  int o = blockIdx.x, b = blockIdx.y;
  int t = threadIdx.x;
  const float* sr = s2 + ((size_t)b * COUT + o) * KN;
  const float* ir = imp + (size_t)b * KN;
  const float* mr = mTK + (size_t)b * KN;
  float s = 0.0f;
  for (int k = t; k < KN; k += 256) s += sr[k] * mr[k] * ir[k];
  __shared__ float red[256];
  red[t] = s;
  __syncthreads();
  for (int st = 128; st > 0; st >>= 1) {
    if (t < st) red[t] += red[t + st];
    __syncthreads();
  }
  if (t == 0) bag[(size_t)b * COUT + o] = red[0];
}

__global__ void pooled_kernel(const float* __restrict__ x, const float* __restrict__ imp,
                              float* __restrict__ pooled) {
  int c = blockIdx.x, b = blockIdx.y;
  int t = threadIdx.x;
  const float* xr = x + ((size_t)b * CIN + c) * KN;
  const float* ir = imp + (size_t)b * KN;
  float s = 0.0f;
  for (int k = t; k < KN; k += 256) s += xr[k] * ir[k];
  __shared__ float red[256];
  red[t] = s;
  __syncthreads();
  for (int st = 128; st > 0; st >>= 1) {
    if (t < st) red[t] += red[t + st];
    __syncthreads();
  }
  if (t == 0) pooled[(size_t)b * CIN + c] = red[0];
}

__global__ void final_kernel(const float* __restrict__ pooled, const float* __restrict__ bag,
                             const float* __restrict__ id_w, const float* __restrict__ id_b,
                             const float* __restrict__ fc_w, float* __restrict__ out) {
  int b = blockIdx.x;
  int o = threadIdx.x;
  __shared__ float v[COUT];
  float s = id_b[o];
  const float* pr = pooled + (size_t)b * CIN;
  for (int c = 0; c < CIN; ++c) s += pr[c] * id_w[(size_t)c * COUT + o];
  v[o] = bag[(size_t)b * COUT + o] + fmaxf(s, 0.0f);
  __syncthreads();
  if (o < NCLS) {
    float acc = 0.0f;
    for (int oo = 0; oo < COUT; ++oo) acc += v[oo] * fc_w[(size_t)oo * NCLS + o];
    out[(size_t)b * NCLS + o] = acc;
  }
}

// ---------------- launch --------------------------------------------------
extern "C" void kernel_launch(void* const* d_in, const int* in_sizes, int n_in,
                              void* d_out, int out_size, void* d_ws, size_t ws_size,
                              hipStream_t stream) {
  const float* x = (const float*)d_in[0];
  const float* imp = (const float*)d_in[1];
  const float* rnd = (const float*)d_in[2];
  const float* W1 = (const float*)d_in[3];
  const float* W2 = (const float*)d_in[4];
  const float* fc_w = (const float*)d_in[5];
  const float* id_w = (const float*)d_in[6];
  const float* id_b = (const float*)d_in[7];
  float* out = (float*)d_out;
  float* emb1 = out + BN_ * NCLS;
  float* bagk = emb1 + (size_t)BN_ * CMID * KN;
  float* bagd = bagk + (size_t)BN_ * CMID;

  float* w = (float*)d_ws;
  size_t off = 0;
  auto take = [&](size_t n) {
    float* p = w + off;
    off += n;
    return p;
  };
  float* invSumP = take((size_t)BN_ * KN);
  float* invNX = take((size_t)BN_ * KN);
  float* invNE = take((size_t)BN_ * KN);
  float* topM = take((size_t)BN_ * KN);
  float* mTK = take((size_t)BN_ * KN);
  float* mTD = take((size_t)BN_ * KN);
  ushort* h = (ushort*)take((size_t)BN_ * CMID * KN / 2);
  ushort* h2 = (ushort*)take((size_t)BN_ * COUT * KN / 2);
  float* s2 = take((size_t)BN_ * COUT * KN);
  float* bag = take((size_t)BN_ * COUT);
  float* pooled = take((size_t)BN_ * CIN);
  ushort* xnT = (ushort*)take((size_t)BN_ * CIN * KN / 2);
  ushort* enT = (ushort*)take((size_t)BN_ * CMID * KN / 2);
  long long avail = (long long)(ws_size / 4) - (long long)off;
  int nb = 1;
  const int cands[6] = {32, 16, 8, 4, 2, 1};
  for (int ci = 0; ci < 6; ++ci) {
    if ((long long)cands[ci] * KN * KN * 3 / 2 <= avail) {
      nb = cands[ci];
      break;
    }
  }
  float* simA = take((size_t)nb * KN * KN);
  ushort* At = (ushort*)take((size_t)nb * KN * KN / 2);

  masks1_kernel<<<dim3(KN / 256, BN_), 256, 0, stream>>>(imp, topM);
  masks2_kernel<<<dim3(KN / 256, BN_), 256, 0, stream>>>(rnd, topM, mTK, mTD);
  psum_kernel<<<dim3(KN / 256, BN_), 256, 0, stream>>>(imp, invSumP);
  colnorm_kernel<CIN><<<(BN_ * KN) / 256, 256, 0, stream>>>(x, invNX);
  xpose_kernel<CIN><<<dim3(KN / 64, CIN / 64, BN_), 256, 0, stream>>>(x, invNX,
                                                                      (__hip_bfloat16*)xnT);
  linear_kernel<CIN, CMID, false><<<(CMID / 8) * BN_, 256, 0, stream>>>(x, W1, h, nullptr);

  for (int bs = 0; bs < BN_; bs += nb) {
    simf_kernel<CIN><<<nb * 64, 256, 0, stream>>>(xnT, simA, bs, nb);
    thrfin_kernel<<<dim3(KN / 4, nb), 256, 0, stream>>>(simA, imp, invSumP, bs);
    at_kernel<<<dim3(KN / 64, KN / 64, nb), 256, 0, stream>>>(simA, At);
    sgemmf_kernel<CMID><<<dim3(KN / 128, CMID / 64, nb), 256, 0, stream>>>(h, At, emb1, bs);
  }

  colnorm_kernel<CMID><<<(BN_ * KN) / 256, 256, 0, stream>>>(emb1, invNE);
  xpose_kernel<CMID><<<dim3(KN / 64, CMID / 64, BN_), 256, 0, stream>>>(emb1, invNE,
                                                                        (__hip_bfloat16*)enT);
  linear_kernel<CMID, COUT, true><<<(COUT / 8) * BN_, 256, 0, stream>>>(emb1, W2, h2, mTK);

  for (int bs = 0; bs < BN_; bs += nb) {
    simf_kernel<CMID><<<nb * 64, 256, 0, stream>>>(enT, simA, bs, nb);
    thrfin_kernel<<<dim3(KN / 4, nb), 256, 0, stream>>>(simA, imp, invSumP, bs);
    at_kernel<<<dim3(KN / 64, KN / 64, nb), 256, 0, stream>>>(simA, At);
    sgemmf_kernel<COUT><<<dim3(KN / 128, COUT / 64, nb), 256, 0, stream>>>(h2, At, s2, bs);
  }

  bag12_kernel<<<dim3(CMID, BN_), 256, 0, stream>>>(emb1, mTK, mTD, imp, bagk, bagd);
  bag2_kernel<<<dim3(COUT, BN_), 256, 0, stream>>>(s2, mTK, imp, bag);
  pooled_kernel<<<dim3(CIN, BN_), 256, 0, stream>>>(x, imp, pooled);
  final_kernel<<<BN_, 64, 0, stream>>>(pooled, bag, id_w, id_b, fc_w, out);
}

// Round 14
// 625.016 us; speedup vs baseline: 1.1629x; 1.0426x over previous
//
#include <hip/hip_runtime.h>
#include <hip/hip_bf16.h>
#include <math.h>

#define BN_ 32
#define CIN 512
#define KN 1024
#define CMID 128
#define COUT 64
#define NCLS 5
#define NUM_TOP 205
#define NUM_KEPT 409
#define NUM_DROP 410
#define ADJ_KK 204
#define EPSF 1e-8f
#define INV_DS (1.0f / 0.599609375f)

typedef __bf16 bf16x8 __attribute__((ext_vector_type(8)));
typedef float f32x4 __attribute__((ext_vector_type(4)));

__device__ inline ushort f2bf(float x) {
  union { __hip_bfloat16 b; ushort u; } c;
  c.b = __float2bfloat16(x);
  return c.u;
}

// async global->LDS, 16B per lane (dest = wave-uniform base + lane*16)
__device__ inline void gll16(const ushort* g, ushort* l) {
  __builtin_amdgcn_global_load_lds(
      (const __attribute__((address_space(1))) unsigned int*)g,
      (__attribute__((address_space(3))) unsigned int*)l, 16, 0, 0);
}

// ---------------- masks stage 1: top mask via rank counting --------------
__global__ __launch_bounds__(256) void masks1_kernel(const float* __restrict__ imp,
                                                     float* __restrict__ topM) {
  int b = blockIdx.y;
  int i = blockIdx.x * 256 + threadIdx.x;
  __shared__ float im[KN];
  for (int j = threadIdx.x; j < KN; j += 256) im[j] = imp[(size_t)b * KN + j];
  __syncthreads();
  float vi = im[i];
  int r0 = 0, r1 = 0, r2 = 0, r3 = 0;
  for (int j = 0; j < KN; j += 4) {
    float a0 = im[j], a1 = im[j + 1], a2 = im[j + 2], a3 = im[j + 3];
    r0 += (a0 > vi || (a0 == vi && j < i)) ? 1 : 0;
    r1 += (a1 > vi || (a1 == vi && j + 1 < i)) ? 1 : 0;
    r2 += (a2 > vi || (a2 == vi && j + 2 < i)) ? 1 : 0;
    r3 += (a3 > vi || (a3 == vi && j + 3 < i)) ? 1 : 0;
  }
  int rank = r0 + r1 + r2 + r3;
  topM[(size_t)b * KN + i] = (rank < NUM_TOP) ? 1.0f : 0.0f;
}

// ---------------- masks stage 2: kept/drop ranks, fused ------------------
__global__ __launch_bounds__(256) void masks2_kernel(const float* __restrict__ rnd,
                                                     const float* __restrict__ topM,
                                                     float* __restrict__ mTK,
                                                     float* __restrict__ mTD) {
  int b = blockIdx.y;
  int i = blockIdx.x * 256 + threadIdx.x;
  __shared__ float r1s[KN];
  __shared__ float r2s[KN];
  for (int j = threadIdx.x; j < KN; j += 256) {
    float tv = topM[(size_t)b * KN + j];
    float rv = rnd[(size_t)b * KN + j];
    r1s[j] = (tv > 0.5f) ? -10.0f : rv;
    r2s[j] = (tv > 0.5f) ? 10.0f : rv;
  }
  __syncthreads();
  float v1 = r1s[i];
  float v2 = r2s[i];
  int c1a = 0, c1b = 0, c2a = 0, c2b = 0;
  for (int j = 0; j < KN; j += 2) {
    float a0 = r1s[j], a1 = r1s[j + 1];
    float b0 = r2s[j], b1 = r2s[j + 1];
    c1a += (a0 > v1 || (a0 == v1 && j < i)) ? 1 : 0;
    c1b += (a1 > v1 || (a1 == v1 && j + 1 < i)) ? 1 : 0;
    c2a += (b0 < v2 || (b0 == v2 && j < i)) ? 1 : 0;
    c2b += (b1 < v2 || (b1 == v2 && j + 1 < i)) ? 1 : 0;
  }
  int kept = (c1a + c1b) < NUM_KEPT;
  int drop = (c2a + c2b) < NUM_DROP;
  int top = topM[(size_t)b * KN + i] > 0.5f;
  mTK[(size_t)b * KN + i] = (top || kept) ? 1.0f : 0.0f;
  mTD[(size_t)b * KN + i] = (top || drop) ? 1.0f : 0.0f;
}

// ---------------- adjP row-sum reciprocals -------------------------------
__global__ void psum_kernel(const float* __restrict__ imp, float* __restrict__ invSumP) {
  int b = blockIdx.y;
  int i = blockIdx.x * 256 + threadIdx.x;
  __shared__ float im[KN];
  for (int j = threadIdx.x; j < KN; j += 256) im[j] = imp[(size_t)b * KN + j];
  __syncthreads();
  float vi = im[i];
  float s = 0.0f;
  for (int j = 0; j < KN; ++j) {
    float d = vi - im[j];
    s += __expf(-d * d * 0.125f);
  }
  invSumP[(size_t)b * KN + i] = 1.0f / (s + 1.0f + EPSF);
}

// ---------------- per-column L2 norm reciprocals -------------------------
template <int C>
__global__ void colnorm_kernel(const float* __restrict__ f, float* __restrict__ inv) {
  int idx = blockIdx.x * 256 + threadIdx.x;
  int b = idx >> 10;
  int k = idx & (KN - 1);
  const float* fb = f + (size_t)b * C * KN + k;
  float ss = 0.0f;
  for (int c = 0; c < C; ++c) {
    float v = fb[(size_t)c * KN];
    ss += v * v;
  }
  inv[idx] = 1.0f / (sqrtf(ss) + EPSF);
}

// ------- transpose + normalize + bf16: oT[b][k][c] = f[b][c][k]*inv[b][k] --
template <int C>
__global__ void xpose_kernel(const float* __restrict__ f, const float* __restrict__ inv,
                             __hip_bfloat16* __restrict__ oT) {
  int b = blockIdx.z;
  int k0 = blockIdx.x * 64;
  int c0 = blockIdx.y * 64;
  __shared__ float t[64][65];
  const float* fb = f + (size_t)b * C * KN;
  int tx = threadIdx.x & 63;
  int ty = threadIdx.x >> 6;
  for (int r = 0; r < 64; r += 4) t[r + ty][tx] = fb[(size_t)(c0 + r + ty) * KN + k0 + tx];
  __syncthreads();
  __hip_bfloat16* ob = oT + (size_t)b * KN * C;
  for (int r = 0; r < 64; r += 4) {
    int k = r + ty;
    float s = inv[(size_t)b * KN + k0 + k];
    ob[(size_t)(k0 + k) * C + c0 + tx] = __float2bfloat16(t[tx][k] * s);
  }
}

// ---------------- MFMA sim: sim = XnT * XnT^T (Gram, symmetric) ----------
template <int C>
__global__ __launch_bounds__(256) void simf_kernel(const ushort* __restrict__ xT,
                                                   float* __restrict__ sim, int bstart, int nb) {
  int f = blockIdx.x;
  int brel, tile;
  if ((nb & 7) == 0) {
    int xcd = f & 7;
    int wdx = f >> 3;
    brel = xcd * (nb >> 3) + (wdx >> 6);
    tile = wdx & 63;
  } else {
    brel = f >> 6;
    tile = f & 63;
  }
  int b = bstart + brel;
  int t = threadIdx.x;
  int lane = t & 63;
  int wid = t >> 6;
  int iB = (tile >> 3) * 128;
  int jB = (tile & 7) * 128;
  const ushort* X = xT + (size_t)b * KN * C;

  __shared__ ushort As[2][128 * 32];
  __shared__ ushort Bs[2][128 * 32];
  __shared__ float ep[4][16][65];

  int srow = t >> 2;
  int scol = (t & 3) * 8;
  int ldst = t * 8;

  auto stage = [&](int buf, int c0) {
    gll16(X + (size_t)(iB + srow) * C + c0 + scol, &As[buf][ldst]);
    gll16(X + (size_t)(iB + 64 + srow) * C + c0 + scol, &As[buf][2048 + ldst]);
    gll16(X + (size_t)(jB + srow) * C + c0 + scol, &Bs[buf][ldst]);
    gll16(X + (size_t)(jB + 64 + srow) * C + c0 + scol, &Bs[buf][2048 + ldst]);
  };

  int i0loc = (wid >> 1) * 64;
  int j0loc = (wid & 1) * 64;
  int r = lane & 15;
  int s = (lane >> 4) * 8;

  f32x4 acc[4][4] = {};
  stage(0, 0);
  __syncthreads();
  constexpr int NT = C / 32;
  int cur = 0;
#pragma unroll 2
  for (int ks = 0; ks < NT; ++ks) {
    if (ks + 1 < NT) stage(cur ^ 1, (ks + 1) * 32);
    bf16x8 a[4], bb[4];
#pragma unroll
    for (int m = 0; m < 4; ++m)
      a[m] = *reinterpret_cast<const bf16x8*>(&As[cur][(i0loc + m * 16 + r) * 32 + s]);
#pragma unroll
    for (int n = 0; n < 4; ++n)
      bb[n] = *reinterpret_cast<const bf16x8*>(&Bs[cur][(j0loc + n * 16 + r) * 32 + s]);
#pragma unroll
    for (int m = 0; m < 4; ++m)
#pragma unroll
      for (int n = 0; n < 4; ++n)
        acc[m][n] = __builtin_amdgcn_mfma_f32_16x16x32_bf16(a[m], bb[n], acc[m][n], 0, 0, 0);
    __syncthreads();
    cur ^= 1;
  }

  float(*buf)[65] = ep[wid];
  int orow = (lane >> 4) * 4;
  int ocol = lane & 15;
  int i0 = iB + i0loc;
  int j0 = jB + j0loc;
  float* simb = sim + (size_t)brel * KN * KN;
#pragma unroll
  for (int m = 0; m < 4; ++m) {
#pragma unroll
    for (int n = 0; n < 4; ++n)
#pragma unroll
      for (int rr = 0; rr < 4; ++rr) buf[orow + rr][n * 16 + ocol] = acc[m][n][rr];
#pragma unroll
    for (int rr = 0; rr < 4; ++rr) {
      int row = rr * 4 + (lane >> 4);
      float4 v4 = *(const float4*)&buf[row][(lane & 15) * 4];
      *(float4*)(simb + (size_t)(i0 + m * 16 + row) * KN + j0 + (lane & 15) * 4) = v4;
    }
  }
}

// ------- fused per-wave threshold select + finalize ----------------------
// Bisection over bits 31..8 (24-bit threshold granularity; tie-bucket
// inclusion differs from exact by ~0.02 entries/row — negligible vs bf16
// input rounding). Count split across pipes: 8 keys ballot+s_bcnt (SALU),
// 8 keys per-lane + shfl reduce (VALU+DS) — balances the shared scalar unit.
__global__ __launch_bounds__(256) void thrfin_kernel(float* __restrict__ A,
                                                     const float* __restrict__ imp,
                                                     const float* __restrict__ invSumP,
                                                     int bstart) {
  int brel = blockIdx.y;
  int b = bstart + brel;
  int wid = threadIdx.x >> 6;
  int lane = threadIdx.x & 63;
  int i = blockIdx.x * 4 + wid;
  float* row = A + ((size_t)brel * KN + i) * KN;
  __shared__ float im[KN];
  ((float4*)im)[threadIdx.x] = ((const float4*)(imp + (size_t)b * KN))[threadIdx.x];
  __syncthreads();

  float4 v[4];
  unsigned key[16];
#pragma unroll
  for (int q = 0; q < 4; ++q) v[q] = ((const float4*)row)[lane + 64 * q];
#pragma unroll
  for (int q = 0; q < 4; ++q) {
    const float* pv = (const float*)&v[q];
#pragma unroll
    for (int e = 0; e < 4; ++e) {
      unsigned u = __float_as_uint(pv[e]);
      key[q * 4 + e] = (u & 0x80000000u) ? ~u : (u | 0x80000000u);
    }
  }
  unsigned tk = 0u;
#pragma unroll 1
  for (int bit = 31; bit >= 8; --bit) {
    unsigned cand = tk | (1u << bit);
    int c = 0;
#pragma unroll
    for (int e = 0; e < 8; ++e)
      c += (int)__popcll(__ballot(key[e] >= cand));
    int cl = 0;
#pragma unroll
    for (int e = 8; e < 16; ++e) cl += (key[e] >= cand) ? 1 : 0;
#pragma unroll
    for (int off = 32; off > 0; off >>= 1) cl += __shfl_xor(cl, off);
    c += cl;
    if (c >= ADJ_KK) tk = cand;
  }
  float m[16];
  float s = 0.0f;
#pragma unroll
  for (int q = 0; q < 4; ++q) {
    const float* pv = (const float*)&v[q];
#pragma unroll
    for (int e = 0; e < 4; ++e) {
      float mv = (key[q * 4 + e] >= tk) ? pv[e] : 0.0f;
      m[q * 4 + e] = mv;
      s += mv;
    }
  }
#pragma unroll
  for (int off = 32; off > 0; off >>= 1) s += __shfl_xor(s, off);
  float invF = 1.0f / (s + 1.0f + EPSF);
  float vi = im[i];
  float invP = invSumP[(size_t)b * KN + i];
  ushort* rowb = (ushort*)row;
#pragma unroll
  for (int q = 0; q < 4; ++q) {
    float4 iv = ((const float4*)im)[lane + 64 * q];
    const float* ip = (const float*)&iv;
    ushort4 r;
    ushort* rp = (ushort*)&r;
    int colb = 4 * lane + 256 * q;
#pragma unroll
    for (int e = 0; e < 4; ++e) {
      float diag = (colb + e == i) ? 1.0f : 0.0f;
      float d = vi - ip[e];
      rp[e] = f2bf((m[q * 4 + e] + diag) * invF + (__expf(-d * d * 0.125f) + diag) * invP);
    }
    ((ushort4*)rowb)[lane + 64 * q] = r;
  }
}

// ------- bf16 transpose: At[b][j][k] = A[b][k][j] (A row stride 2048) ----
__global__ void at_kernel(const float* __restrict__ Asim, ushort* __restrict__ At) {
  int brel = blockIdx.z;
  int k0 = blockIdx.x * 64;
  int j0 = blockIdx.y * 64;
  __shared__ ushort t[64][65];
  const ushort* Ab = (const ushort*)(Asim + (size_t)brel * KN * KN);
  int tx = threadIdx.x & 63;
  int ty = threadIdx.x >> 6;
  for (int r = 0; r < 64; r += 4) t[r + ty][tx] = Ab[(size_t)(k0 + r + ty) * 2048 + j0 + tx];
  __syncthreads();
  ushort* ob = At + (size_t)brel * KN * KN;
  for (int r = 0; r < 64; r += 4) ob[(size_t)(j0 + r + ty) * KN + k0 + tx] = t[tx][r + ty];
}

// ---------------- per-node linear: h[b,o,k] = sum_c f[b,c,k] W[c,o] (bf16 out)
// o-tile = 8: 16KB LDS Ws tile, grid (M/8)*32 (2 blk/CU), b-major flat grid
// (stride 32 = 0 mod 8) keeps batch b's blocks on one XCD sharing x[b] in L2.
template <int C, int M, bool MASK>
__global__ __launch_bounds__(256) void linear_kernel(const float* __restrict__ f,
                                                     const float* __restrict__ W,
                                                     ushort* __restrict__ outp,
                                                     const float* __restrict__ mTK) {
  int fl = blockIdx.x;
  int b = fl & 31;
  int o0 = (fl >> 5) * 8;
  __shared__ float Ws[C][8];
  for (int l = threadIdx.x; l < C * 8; l += 256) {
    int c = l >> 3, o = l & 7;
    Ws[c][o] = W[(size_t)c * M + o0 + o];
  }
  __syncthreads();
  int k0 = threadIdx.x * 4;
  const float* fb = f + (size_t)b * C * KN;
  float acc[8][4] = {};
  for (int c = 0; c < C; ++c) {
    float4 xv = *(const float4*)(fb + (size_t)c * KN + k0);
#pragma unroll
    for (int o = 0; o < 8; ++o) {
      float w = Ws[c][o];
      acc[o][0] += xv.x * w;
      acc[o][1] += xv.y * w;
      acc[o][2] += xv.z * w;
      acc[o][3] += xv.w * w;
    }
  }
  float ms[4] = {1.0f, 1.0f, 1.0f, 1.0f};
  if (MASK) {
#pragma unroll
    for (int jj = 0; jj < 4; ++jj) ms[jj] = mTK[(size_t)b * KN + k0 + jj] * INV_DS;
  }
#pragma unroll
  for (int o = 0; o < 8; ++o) {
    ushort4 r;
    r.x = f2bf(acc[o][0] * ms[0]);
    r.y = f2bf(acc[o][1] * ms[1]);
    r.z = f2bf(acc[o][2] * ms[2]);
    r.w = f2bf(acc[o][3] * ms[3]);
    *(ushort4*)(outp + ((size_t)b * M + o0 + o) * KN + k0) = r;
  }
}

// ---------------- MFMA s = relu(h @ A) via At, LDS-staged ----------------
template <int M>
__global__ __launch_bounds__(256) void sgemmf_kernel(const ushort* __restrict__ hB,
                                                     const ushort* __restrict__ At,
                                                     float* __restrict__ outp, int bstart) {
  int brel = blockIdx.z;
  int b = bstart + brel;
  int t = threadIdx.x;
  int lane = t & 63;
  int wid = t >> 6;
  int iB = blockIdx.y * 64;
  int jB = blockIdx.x * 128;
  const ushort* hb = hB + (size_t)b * M * KN;
  const ushort* Ab = At + (size_t)brel * KN * KN;

  __shared__ ushort Hs[2][64 * 32];
  __shared__ ushort Bs[2][128 * 32];
  __shared__ float ep[4][16][65];

  int srow = t >> 2;
  int scol = (t & 3) * 8;
  int ldst = t * 8;

  auto stage = [&](int buf, int k0) {
    gll16(hb + (size_t)(iB + srow) * KN + k0 + scol, &Hs[buf][ldst]);
    gll16(Ab + (size_t)(jB + srow) * KN + k0 + scol, &Bs[buf][ldst]);
    gll16(Ab + (size_t)(jB + 64 + srow) * KN + k0 + scol, &Bs[buf][2048 + ldst]);
  };

  int i0loc = (wid >> 1) * 32;
  int j0loc = (wid & 1) * 64;
  int r = lane & 15;
  int s = (lane >> 4) * 8;

  f32x4 acc[2][4] = {};
  stage(0, 0);
  __syncthreads();
  int cur = 0;
#pragma unroll 2
  for (int ks = 0; ks < KN / 32; ++ks) {
    if (ks + 1 < KN / 32) stage(cur ^ 1, (ks + 1) * 32);
    bf16x8 a[2], bb[4];
#pragma unroll
    for (int m = 0; m < 2; ++m)
      a[m] = *reinterpret_cast<const bf16x8*>(&Hs[cur][(i0loc + m * 16 + r) * 32 + s]);
#pragma unroll
    for (int n = 0; n < 4; ++n)
      bb[n] = *reinterpret_cast<const bf16x8*>(&Bs[cur][(j0loc + n * 16 + r) * 32 + s]);
#pragma unroll
    for (int m = 0; m < 2; ++m)
#pragma unroll
      for (int n = 0; n < 4; ++n)
        acc[m][n] = __builtin_amdgcn_mfma_f32_16x16x32_bf16(a[m], bb[n], acc[m][n], 0, 0, 0);
    __syncthreads();
    cur ^= 1;
  }

  float(*buf)[65] = ep[wid];
  int orow = (lane >> 4) * 4;
  int ocol = lane & 15;
  int i0 = iB + i0loc;
  int j0 = jB + j0loc;
  float* ob = outp + (size_t)b * M * KN;
#pragma unroll
  for (int m = 0; m < 2; ++m) {
#pragma unroll
    for (int n = 0; n < 4; ++n)
#pragma unroll
      for (int rr = 0; rr < 4; ++rr) buf[orow + rr][n * 16 + ocol] = fmaxf(acc[m][n][rr], 0.0f);
#pragma unroll
    for (int rr = 0; rr < 4; ++rr) {
      int row = rr * 4 + (lane >> 4);
      float4 v4 = *(const float4*)&buf[row][(lane & 15) * 4];
      *(float4*)(ob + (size_t)(i0 + m * 16 + row) * KN + j0 + (lane & 15) * 4) = v4;
    }
  }
}

// ---------------- reductions ---------------------------------------------
__global__ void bag12_kernel(const float* __restrict__ emb1, const float* __restrict__ mTK,
                             const float* __restrict__ mTD, const float* __restrict__ imp,
                             float* __restrict__ bagk, float* __restrict__ bagd) {
  int c = blockIdx.x, b = blockIdx.y;
  int t = threadIdx.x;
  const float* e = emb1 + ((size_t)b * CMID + c) * KN;
  const float* ir = imp + (size_t)b * KN;
  const float* m1 = mTK + (size_t)b * KN;
  const float* m2 = mTD + (size_t)b * KN;
  float s1 = 0.0f, sd = 0.0f;
  for (int k = t; k < KN; k += 256) {
    float ev = e[k] * ir[k];
    s1 += ev * m1[k];
    sd += ev * m2[k];
  }
  __shared__ float r1[256], r2[256];
  r1[t] = s1;
  r2[t] = sd;
  __syncthreads();
  for (int st = 128; st > 0; st >>= 1) {
    if (t < st) {
      r1[t] += r1[t + st];
      r2[t] += r2[t + st];
    }
    __syncthreads();
  }
  if (t == 0) {
    bagk[(size_t)b * CMID + c] = r1[0] * INV_DS;
    bagd[(size_t)b * CMID + c] = r2[0] * INV_DS;
  }
}

__global__ void bag2_kernel(const float* __restrict__ s2, const float* __restrict__ mTK,
                            const float* __restrict__ imp, float* __restrict__ bag) {
  int o = blockIdx.x, b = blockIdx.y;
  int t = threadIdx.x;
  const float* sr = s2 + ((size_t)b * COUT + o) * KN;
  const float* ir = imp + (size_t)b * KN;
  const float* mr = mTK + (size_t)b * KN;
  float s = 0.0f;
  for (int k = t; k < KN; k += 256) s += sr[k] * mr[k] * ir[k];
  __shared__ float red[256];
  red[t] = s;
  __syncthreads();
  for (int st = 128; st > 0; st >>= 1) {
    if (t < st) red[t] += red[t + st];
    __syncthreads();
  }
  if (t == 0) bag[(size_t)b * COUT + o] = red[0];
}

__global__ void pooled_kernel(const float* __restrict__ x, const float* __restrict__ imp,
                              float* __restrict__ pooled) {
  int c = blockIdx.x, b = blockIdx.y;
  int t = threadIdx.x;
  const float* xr = x + ((size_t)b * CIN + c) * KN;
  const float* ir = imp + (size_t)b * KN;
  float s = 0.0f;
  for (int k = t; k < KN; k += 256) s += xr[k] * ir[k];
  __shared__ float red[256];
  red[t] = s;
  __syncthreads();
  for (int st = 128; st > 0; st >>= 1) {
    if (t < st) red[t] += red[t + st];
    __syncthreads();
  }
  if (t == 0) pooled[(size_t)b * CIN + c] = red[0];
}

__global__ void final_kernel(const float* __restrict__ pooled, const float* __restrict__ bag,
                             const float* __restrict__ id_w, const float* __restrict__ id_b,
                             const float* __restrict__ fc_w, float* __restrict__ out) {
  int b = blockIdx.x;
  int o = threadIdx.x;
  __shared__ float v[COUT];
  float s = id_b[o];
  const float* pr = pooled + (size_t)b * CIN;
  for (int c = 0; c < CIN; ++c) s += pr[c] * id_w[(size_t)c * COUT + o];
  v[o] = bag[(size_t)b * COUT + o] + fmaxf(s, 0.0f);
  __syncthreads();
  if (o < NCLS) {
    float acc = 0.0f;
    for (int oo = 0; oo < COUT; ++oo) acc += v[oo] * fc_w[(size_t)oo * NCLS + o];
    out[(size_t)b * NCLS + o] = acc;
  }
}

// ---------------- launch --------------------------------------------------
extern "C" void kernel_launch(void* const* d_in, const int* in_sizes, int n_in,
                              void* d_out, int out_size, void* d_ws, size_t ws_size,
                              hipStream_t stream) {
  const float* x = (const float*)d_in[0];
  const float* imp = (const float*)d_in[1];
  const float* rnd = (const float*)d_in[2];
  const float* W1 = (const float*)d_in[3];
  const float* W2 = (const float*)d_in[4];
  const float* fc_w = (const float*)d_in[5];
  const float* id_w = (const float*)d_in[6];
  const float* id_b = (const float*)d_in[7];
  float* out = (float*)d_out;
  float* emb1 = out + BN_ * NCLS;
  float* bagk = emb1 + (size_t)BN_ * CMID * KN;
  float* bagd = bagk + (size_t)BN_ * CMID;

  float* w = (float*)d_ws;
  size_t off = 0;
  auto take = [&](size_t n) {
    float* p = w + off;
    off += n;
    return p;
  };
  float* invSumP = take((size_t)BN_ * KN);
  float* invNX = take((size_t)BN_ * KN);
  float* invNE = take((size_t)BN_ * KN);
  float* topM = take((size_t)BN_ * KN);
  float* mTK = take((size_t)BN_ * KN);
  float* mTD = take((size_t)BN_ * KN);
  ushort* h = (ushort*)take((size_t)BN_ * CMID * KN / 2);
  ushort* h2 = (ushort*)take((size_t)BN_ * COUT * KN / 2);
  float* s2 = take((size_t)BN_ * COUT * KN);
  float* bag = take((size_t)BN_ * COUT);
  float* pooled = take((size_t)BN_ * CIN);
  ushort* xnT = (ushort*)take((size_t)BN_ * CIN * KN / 2);
  ushort* enT = (ushort*)take((size_t)BN_ * CMID * KN / 2);
  long long avail = (long long)(ws_size / 4) - (long long)off;
  int nb = 1;
  const int cands[6] = {32, 16, 8, 4, 2, 1};
  for (int ci = 0; ci < 6; ++ci) {
    if ((long long)cands[ci] * KN * KN * 3 / 2 <= avail) {
      nb = cands[ci];
      break;
    }
  }
  float* simA = take((size_t)nb * KN * KN);
  ushort* At = (ushort*)take((size_t)nb * KN * KN / 2);

  masks1_kernel<<<dim3(KN / 256, BN_), 256, 0, stream>>>(imp, topM);
  masks2_kernel<<<dim3(KN / 256, BN_), 256, 0, stream>>>(rnd, topM, mTK, mTD);
  psum_kernel<<<dim3(KN / 256, BN_), 256, 0, stream>>>(imp, invSumP);
  colnorm_kernel<CIN><<<(BN_ * KN) / 256, 256, 0, stream>>>(x, invNX);
  xpose_kernel<CIN><<<dim3(KN / 64, CIN / 64, BN_), 256, 0, stream>>>(x, invNX,
                                                                      (__hip_bfloat16*)xnT);
  linear_kernel<CIN, CMID, false><<<(CMID / 8) * BN_, 256, 0, stream>>>(x, W1, h, nullptr);

  for (int bs = 0; bs < BN_; bs += nb) {
    simf_kernel<CIN><<<nb * 64, 256, 0, stream>>>(xnT, simA, bs, nb);
    thrfin_kernel<<<dim3(KN / 4, nb), 256, 0, stream>>>(simA, imp, invSumP, bs);
    at_kernel<<<dim3(KN / 64, KN / 64, nb), 256, 0, stream>>>(simA, At);
    sgemmf_kernel<CMID><<<dim3(KN / 128, CMID / 64, nb), 256, 0, stream>>>(h, At, emb1, bs);
  }

  colnorm_kernel<CMID><<<(BN_ * KN) / 256, 256, 0, stream>>>(emb1, invNE);
  xpose_kernel<CMID><<<dim3(KN / 64, CMID / 64, BN_), 256, 0, stream>>>(emb1, invNE,
                                                                        (__hip_bfloat16*)enT);
  linear_kernel<CMID, COUT, true><<<(COUT / 8) * BN_, 256, 0, stream>>>(emb1, W2, h2, mTK);

  for (int bs = 0; bs < BN_; bs += nb) {
    simf_kernel<CMID><<<nb * 64, 256, 0, stream>>>(enT, simA, bs, nb);
    thrfin_kernel<<<dim3(KN / 4, nb), 256, 0, stream>>>(simA, imp, invSumP, bs);
    at_kernel<<<dim3(KN / 64, KN / 64, nb), 256, 0, stream>>>(simA, At);
    sgemmf_kernel<COUT><<<dim3(KN / 128, COUT / 64, nb), 256, 0, stream>>>(h2, At, s2, bs);
  }

  bag12_kernel<<<dim3(CMID, BN_), 256, 0, stream>>>(emb1, mTK, mTD, imp, bagk, bagd);
  bag2_kernel<<<dim3(COUT, BN_), 256, 0, stream>>>(s2, mTK, imp, bag);
  pooled_kernel<<<dim3(CIN, BN_), 256, 0, stream>>>(x, imp, pooled);
  final_kernel<<<BN_, 64, 0, stream>>>(pooled, bag, id_w, id_b, fc_w, out);
}